// Round 3
// baseline (19750.768 us; speedup 1.0000x reference)
//
#include <hip/hip_runtime.h>

#define S_LEN 256
#define B_SZ  256
#define N_MEM 128
#define D_DIM 256
#define C_DIM 512
#define NBLK  256

typedef __bf16 bf16x8 __attribute__((ext_vector_type(8)));
typedef unsigned short ushort8 __attribute__((ext_vector_type(8)));
typedef unsigned short ushort4v __attribute__((ext_vector_type(4)));
typedef float floatx4 __attribute__((ext_vector_type(4)));
typedef float floatx2 __attribute__((ext_vector_type(2)));

__device__ __forceinline__ unsigned short f2bf(float f){
  unsigned u = __float_as_uint(f);
  u += 0x7FFFu + ((u >> 16) & 1u);
  return (unsigned short)(u >> 16);
}
__device__ __forceinline__ float sigm(float x){ return 1.f/(1.f + __expf(-x)); }

__device__ __forceinline__ floatx4 mfma16(bf16x8 a, bf16x8 b, floatx4 c){
  return __builtin_amdgcn_mfma_f32_16x16x32_bf16(a, b, c, 0, 0, 0);
}

// ---------------- prologue kernels (once per call) ----------------

// cast x to bf16
__global__ __launch_bounds__(256) void p0_xbf(const float* __restrict__ x,
                                              unsigned short* __restrict__ xbf){
  int idx = (blockIdx.x*256 + threadIdx.x)*4;
  floatx4 f = *(const floatx4*)(x + idx);
  ushort4v u;
  u[0]=f2bf(f[0]); u[1]=f2bf(f[1]); u[2]=f2bf(f[2]); u[3]=f2bf(f[3]);
  *(ushort4v*)(xbf + idx) = u;
}

// Wg[n][k] = bf16( k<256 ? W_ih[n][k] : W_hh[n][k-256] )   (2048 x 768)
__global__ __launch_bounds__(256) void p1_wg(const float* __restrict__ Wih,
                                             const float* __restrict__ Whh,
                                             unsigned short* __restrict__ Wg){
  int idx = blockIdx.x*256 + threadIdx.x;
  int n = idx / 768, k = idx - n*768;
  float v = (k < 256) ? Wih[n*256 + k] : Whh[n*512 + (k-256)];
  Wg[idx] = f2bf(v);
}

// T[e][c] = sum_d' Wq[e][d'] * W_read[d'][c]; rq[e] = bq[e] + b_read . Wq[e,:]
__global__ __launch_bounds__(256) void p2_T(const float* __restrict__ Win,
                                            const float* __restrict__ Wread,
                                            const float* __restrict__ bread,
                                            const float* __restrict__ bin,
                                            float* __restrict__ T, float* __restrict__ rq){
  if (blockIdx.x < 512){
    int idx = blockIdx.x*256 + threadIdx.x;
    int e = idx >> 9, cc = idx & 511;
    float acc = 0.f;
    for (int dp = 0; dp < 256; ++dp) acc += Win[e*256 + dp] * Wread[dp*512 + cc];
    T[idx] = acc;
  } else {
    int e = threadIdx.x;
    float acc = bin[e];
    for (int dp = 0; dp < 256; ++dp) acc += bread[dp] * Win[e*256 + dp];
    rq[e] = acc;
  }
}

// W2 (1808 x 512) bf16 + bias2[1808]
__global__ __launch_bounds__(256) void p3_w2(const float* __restrict__ Win,
                                             const float* __restrict__ Wwrite,
                                             const float* __restrict__ Werase,
                                             const float* __restrict__ Wrg,
                                             const float* __restrict__ Wwg,
                                             const float* __restrict__ bwrite,
                                             const float* __restrict__ berase,
                                             const float* __restrict__ brg,
                                             const float* __restrict__ bwg,
                                             const float* __restrict__ T,
                                             const float* __restrict__ rq,
                                             unsigned short* __restrict__ W2,
                                             float* __restrict__ bias2){
  int bid = blockIdx.x;
  if (bid < 2048){
    int idx = bid*256 + threadIdx.x;
    int j = idx >> 9, cc = idx & 511;
    int h = j >> 8, d = j & 255;
    float acc = 0.f;
    const float* wk = Win + (256 + h*64)*256 + d;
    const float* tp = T + (h*64)*512 + cc;
    for (int i = 0; i < 64; ++i) acc += wk[i*256] * tp[i*512];
    W2[(size_t)j*512 + cc] = f2bf(acc);
  } else if (bid < 2048 + 1568){
    int idx = (bid - 2048)*256 + threadIdx.x;
    int r = idx >> 9, cc = idx & 511;
    float v;
    if      (r < 512) v = Wwrite[r*512 + cc];
    else if (r < 768) v = Werase[(r-512)*512 + cc];
    else if (r == 768) v = Wrg[cc];
    else if (r == 769) v = Wwg[cc];
    else v = 0.f;
    W2[(size_t)(1024 + r)*512 + cc] = f2bf(v);
  } else {
    int j = (bid - 2048 - 1568)*256 + threadIdx.x;
    if (j >= 1808) return;
    float v;
    if (j < 1024){
      int h = j >> 8, d = j & 255;
      float acc = 0.f;
      for (int i = 0; i < 64; ++i) acc += rq[h*64+i] * Win[(256 + h*64 + i)*256 + d];
      v = acc;
    }
    else if (j < 1536) v = bwrite[j - 1024];
    else if (j < 1792) v = berase[j - 1536];
    else if (j == 1792) v = brg[0];
    else if (j == 1793) v = bwg[0];
    else v = 0.f;
    bias2[j] = v;
  }
}

// Fold (256 x 1024) bf16 + bout2[256]
__global__ __launch_bounds__(256) void p4_fold(const float* __restrict__ Win,
                                               const float* __restrict__ Wout,
                                               const float* __restrict__ bout,
                                               const float* __restrict__ bin,
                                               unsigned short* __restrict__ Fold,
                                               float* __restrict__ bout2){
  if (blockIdx.x < 1024){
    int idx = blockIdx.x*256 + threadIdx.x;
    int dp = idx >> 10, j = idx & 1023;
    int h = j >> 8, d = j & 255;
    float acc = 0.f;
    const float* wv = Win + (512 + h*64)*256 + d;
    const float* wo = Wout + dp*256 + h*64;
    for (int i = 0; i < 64; ++i) acc += wv[i*256] * wo[i];
    Fold[(size_t)dp*1024 + j] = f2bf(acc);
  } else {
    int dp = threadIdx.x;
    float acc = bout[dp];
    for (int e = 0; e < 256; ++e) acc += Wout[dp*256 + e] * bin[512 + e];
    bout2[dp] = acc;
  }
}

// zero c and h0
__global__ __launch_bounds__(256) void p5_init(float* __restrict__ c,
                                               unsigned short* __restrict__ h0){
  int idx = blockIdx.x*256 + threadIdx.x;
  c[idx] = 0.f; h0[idx] = 0;
}

// ---------------- persistent kernel with software grid barrier ----------------

__device__ __forceinline__ void gbar(unsigned* cnt, unsigned expected){
  __syncthreads();
  if (threadIdx.x == 0){
    __threadfence();
    atomicAdd(cnt, 1u);
    while (atomicAdd(cnt, 0u) < expected) __builtin_amdgcn_s_sleep(4);
    __threadfence();
  }
  __syncthreads();
}

__device__ __forceinline__ void do_readout(int jj, int t,
                                           const unsigned short* __restrict__ mctx,
                                           const unsigned short* __restrict__ Fold,
                                           const float* __restrict__ rgbuf,
                                           const float* __restrict__ bout2,
                                           const float* __restrict__ x,
                                           float* __restrict__ out, int lane){
  const int mt = jj & 15, dt = jj >> 4;
  const int lm = lane & 15, lk = (lane >> 4) * 8;
  const unsigned short* ap = mctx + (size_t)(mt*16 + lm)*1024 + lk;
  const unsigned short* bp = Fold + (size_t)(dt*16 + lm)*1024 + lk;
  floatx4 acc = {0,0,0,0};
  #pragma unroll
  for (int kt = 0; kt < 32; ++kt)
    acc = mfma16(*(const bf16x8*)(ap + kt*32), *(const bf16x8*)(bp + kt*32), acc);
  const int r0 = mt*16 + ((lane >> 4) << 2);
  const int dp = dt*16 + lm;
  const float bo = bout2[dp];
  #pragma unroll
  for (int r = 0; r < 4; ++r){
    const int bb = r0 + r;
    const size_t oi = ((size_t)bb * S_LEN + (t-1)) * D_DIM + dp;
    out[oi] = x[oi] + rgbuf[bb] * (acc[r] + bo);
  }
}

__global__ __launch_bounds__(512) void kmain(
    const float* __restrict__ x,
    const unsigned short* __restrict__ xbf,
    const unsigned short* __restrict__ Wg,
    const float* __restrict__ bih, const float* __restrict__ bhh,
    const unsigned short* __restrict__ W2, const float* __restrict__ bias2,
    const unsigned short* __restrict__ Fold, const float* __restrict__ bout2,
    float* __restrict__ cbuf,
    unsigned short* __restrict__ h0buf, unsigned short* __restrict__ h1buf,
    float* __restrict__ proj, unsigned short* __restrict__ mctx,
    float* __restrict__ rgbuf, const float* __restrict__ mem0,
    float* __restrict__ memT, float* __restrict__ out,
    unsigned* __restrict__ barcnt)
{
  const int bid = blockIdx.x, tid = threadIdx.x;
  const int lane = tid & 63, wave = tid >> 6;
  const int lm = lane & 15, lk = (lane >> 4) * 8;

  __shared__ float memL[128][258];     // 132096 B
  __shared__ float ga[4][16][32];      //   8192 B
  __shared__ float qk4[4][256];        //   4096 B
  __shared__ float wk[256], wvs[256], er[256]; // 3072 B
  __shared__ float sc[5][512];         //  10240 B
  __shared__ float at[5][128];         //   2560 B

  // load this batch's memory into LDS (identical broadcast of mem0)
  for (int i = tid; i < 32768; i += 512) memL[i >> 8][i & 255] = mem0[i];

  unsigned nbar = 0;
  const unsigned short* hr = h0buf;
  unsigned short* hw = h1buf;
  const int r = bid >> 4, uc = bid & 15, u0 = uc*32;
  const int g = wave >> 1, colh = wave & 1;

  for (int t = 0; t < S_LEN; ++t){
    // ---- phase AB: gates GEMM (block = 16 rows x 32 units x 4 quadrants) + LSTM ----
    {
      const int row = r*16 + lm;
      const unsigned short* ax = xbf + ((size_t)row*S_LEN + t)*D_DIM + lk;
      const unsigned short* ah = hr + (size_t)row*C_DIM + lk;
      const unsigned short* wb = Wg + (size_t)(g*512 + u0 + colh*16 + lm)*768 + lk;
      floatx4 acc = {0,0,0,0};
      #pragma unroll
      for (int kt = 0; kt < 8; ++kt)
        acc = mfma16(*(const bf16x8*)(ax + kt*32), *(const bf16x8*)(wb + kt*32), acc);
      #pragma unroll
      for (int kt = 0; kt < 16; ++kt)
        acc = mfma16(*(const bf16x8*)(ah + kt*32), *(const bf16x8*)(wb + 256 + kt*32), acc);
      const int rr0 = (lane >> 4) << 2;
      #pragma unroll
      for (int q = 0; q < 4; ++q) ga[g][rr0+q][colh*16 + lm] = acc[q];
      __syncthreads();
      {
        const int ri = tid >> 5, ci = tid & 31;
        const int b = r*16 + ri, u = u0 + ci;
        const float gi = ga[0][ri][ci] + bih[u]        + bhh[u];
        const float gf = ga[1][ri][ci] + bih[512 + u]  + bhh[512 + u];
        const float gg = ga[2][ri][ci] + bih[1024 + u] + bhh[1024 + u];
        const float go = ga[3][ri][ci] + bih[1536 + u] + bhh[1536 + u];
        const int ci2 = b*512 + u;
        const float cn = sigm(gf) * cbuf[ci2] + sigm(gi) * tanhf(gg);
        cbuf[ci2] = cn;
        hw[ci2] = f2bf(sigm(go) * tanhf(cn));
      }
    }
    gbar(barcnt, ++nbar * NBLK);
    // ---- phase C: proj GEMM + readout(t-1) ----
    {
      for (int jid = bid*8 + wave; jid < 2064; jid += 2048){
        if (jid < 1808){
          const int mt = jid & 15, nt = jid >> 4;
          const unsigned short* ap = hw + (size_t)(mt*16 + lm)*512 + lk;
          const unsigned short* bp = W2 + (size_t)(nt*16 + lm)*512 + lk;
          floatx4 acc = {0,0,0,0};
          #pragma unroll
          for (int kt = 0; kt < 16; ++kt)
            acc = mfma16(*(const bf16x8*)(ap + kt*32), *(const bf16x8*)(bp + kt*32), acc);
          const int r0 = mt*16 + ((lane >> 4) << 2);
          const int cc = nt*16 + lm;
          const float bv = bias2[cc];
          const bool sg = (cc >= 1536 && cc < 1794);
          #pragma unroll
          for (int q = 0; q < 4; ++q){
            float v = acc[q] + bv;
            if (sg) v = sigm(v);
            proj[(size_t)(r0 + q)*1808 + cc] = v;
          }
        } else if (t >= 1){
          do_readout(jid - 1808, t, mctx, Fold, rgbuf, bout2, x, out, lane);
        }
      }
    }
    gbar(barcnt, ++nbar * NBLK);
    // ---- phase D: attention + memory update (block = batch bid, mem in LDS) ----
    {
      const float* prow = proj + (size_t)bid * 1808;
      for (int i = tid; i < 1024; i += 512) qk4[i >> 8][i & 255] = prow[i];
      if (tid < 256){ wk[tid] = prow[1024 + tid]; er[tid] = prow[1536 + tid]; }
      else          { wvs[tid - 256] = prow[1280 + (tid - 256)]; }
      const float wgv = prow[1793];
      if (tid == 0) rgbuf[bid] = prow[1792];
      __syncthreads();
      // pass1: scores
      {
        const int n = tid & 127, quarter = tid >> 7, db = quarter*64;
        const float* mr = &memL[n][db];
        float a0=0,a1=0,a2=0,a3=0,a4=0;
        #pragma unroll 8
        for (int i = 0; i < 64; i += 2){
          floatx2 m2 = *(const floatx2*)(mr + i);
          a0 += m2[0]*qk4[0][db+i] + m2[1]*qk4[0][db+i+1];
          a1 += m2[0]*qk4[1][db+i] + m2[1]*qk4[1][db+i+1];
          a2 += m2[0]*qk4[2][db+i] + m2[1]*qk4[2][db+i+1];
          a3 += m2[0]*qk4[3][db+i] + m2[1]*qk4[3][db+i+1];
          a4 += m2[0]*wk[db+i]     + m2[1]*wk[db+i+1];
        }
        sc[0][tid]=a0; sc[1][tid]=a1; sc[2][tid]=a2; sc[3][tid]=a3; sc[4][tid]=a4;
      }
      __syncthreads();
      if (tid < 128){
        #pragma unroll
        for (int j = 0; j < 5; ++j){
          float v = sc[j][tid] + sc[j][tid+128] + sc[j][tid+256] + sc[j][tid+384];
          sc[j][tid] = (j < 4) ? v * 0.125f : v;
        }
      }
      __syncthreads();
      {
        const int w = tid >> 6, l = tid & 63;
        if (w < 5){
          const int j = w;
          float v0 = sc[j][l], v1 = sc[j][l + 64];
          float mx = fmaxf(v0, v1);
          #pragma unroll
          for (int off = 32; off; off >>= 1) mx = fmaxf(mx, __shfl_xor(mx, off));
          float e0 = __expf(v0 - mx), e1 = __expf(v1 - mx);
          float sm = e0 + e1;
          #pragma unroll
          for (int off = 32; off; off >>= 1) sm += __shfl_xor(sm, off);
          float inv = 1.f / sm;
          at[j][l] = e0 * inv; at[j][l + 64] = e1 * inv;
        }
      }
      __syncthreads();
      // mctx accumulate (threads 0..255, one d each)
      if (tid < 256){
        const int d = tid;
        float m0=0,m1=0,m2=0,m3=0;
        #pragma unroll 4
        for (int n = 0; n < N_MEM; ++n){
          float m = memL[n][d];
          m0 += at[0][n] * m;
          m1 += at[1][n] * m;
          m2 += at[2][n] * m;
          m3 += at[3][n] * m;
        }
        unsigned short* mr2 = mctx + (size_t)bid * 1024;
        mr2[d] = f2bf(m0); mr2[256+d] = f2bf(m1); mr2[512+d] = f2bf(m2); mr2[768+d] = f2bf(m3);
      }
      __syncthreads();
      // memory erase/write update (all 512 threads)
      for (int idx = tid; idx < 32768; idx += 512){
        const int n = idx >> 8, d = idx & 255;
        const float a = at[4][n];
        memL[n][d] = memL[n][d] * (1.f - a * er[d]) + wgv * (a * wvs[d]);
      }
    }
    // swap h buffers
    unsigned short* tmp = (unsigned short*)hr; hr = hw; hw = tmp;
  }
  gbar(barcnt, ++nbar * NBLK);
  // final readout (t = S_LEN)
  {
    const int slot = bid*8 + wave;
    if (slot < 256) do_readout(slot, S_LEN, mctx, Fold, rgbuf, bout2, x, out, lane);
  }
  // write final memory state
  for (int i = tid; i < 32768; i += 512)
    memT[(size_t)bid * 32768 + i] = memL[i >> 8][i & 255];
}

// ---------------- host ----------------

extern "C" void kernel_launch(void* const* d_in, const int* in_sizes, int n_in,
                              void* d_out, int out_size, void* d_ws, size_t ws_size,
                              hipStream_t stream){
  const float* x      = (const float*)d_in[0];
  const float* mem0   = (const float*)d_in[1];
  const float* Wih    = (const float*)d_in[2];
  const float* Whh    = (const float*)d_in[3];
  const float* bih    = (const float*)d_in[4];
  const float* bhh    = (const float*)d_in[5];
  const float* Wread  = (const float*)d_in[6];
  const float* bread  = (const float*)d_in[7];
  const float* Wwrite = (const float*)d_in[8];
  const float* bwrite = (const float*)d_in[9];
  const float* Werase = (const float*)d_in[10];
  const float* berase = (const float*)d_in[11];
  const float* Win    = (const float*)d_in[12];
  const float* bin    = (const float*)d_in[13];
  const float* Wout   = (const float*)d_in[14];
  const float* bout   = (const float*)d_in[15];
  const float* Wrg    = (const float*)d_in[16];
  const float* brg    = (const float*)d_in[17];
  const float* Wwg    = (const float*)d_in[18];
  const float* bwg    = (const float*)d_in[19];
  float* out = (float*)d_out;
  float* memT = out + (size_t)B_SZ * S_LEN * D_DIM;

  char* ws = (char*)d_ws;
  size_t off = 0;
  auto alloc = [&](size_t bytes) -> void* {
    void* p = ws + off; off += (bytes + 511) & ~(size_t)511; return p;
  };
  unsigned short* xbf  = (unsigned short*)alloc((size_t)B_SZ*S_LEN*D_DIM*2);
  unsigned short* Wg   = (unsigned short*)alloc((size_t)2048*768*2);
  unsigned short* W2   = (unsigned short*)alloc((size_t)1808*512*2);
  unsigned short* Fold = (unsigned short*)alloc((size_t)256*1024*2);
  float* T     = (float*)alloc((size_t)256*512*4);
  float* rq    = (float*)alloc(256*4);
  float* bias2 = (float*)alloc(1808*4);
  float* bout2 = (float*)alloc(256*4);
  float* cbuf  = (float*)alloc((size_t)256*512*4);
  unsigned short* h0 = (unsigned short*)alloc((size_t)256*512*2);
  unsigned short* h1 = (unsigned short*)alloc((size_t)256*512*2);
  float* proj  = (float*)alloc((size_t)256*1808*4);
  unsigned short* mctx = (unsigned short*)alloc((size_t)256*1024*2);
  float* rgbuf = (float*)alloc(256*4);
  unsigned* barcnt = (unsigned*)alloc(256);
  (void)ws_size; (void)in_sizes; (void)n_in; (void)out_size;

  hipMemsetAsync(barcnt, 0, 64, stream);
  p0_xbf <<<16384, 256, 0, stream>>>(x, xbf);
  p1_wg  <<<6144, 256, 0, stream>>>(Wih, Whh, Wg);
  p2_T   <<<513,  256, 0, stream>>>(Win, Wread, bread, bin, T, rq);
  p3_w2  <<<3624, 256, 0, stream>>>(Win, Wwrite, Werase, Wrg, Wwg, bwrite, berase, brg, bwg, T, rq, W2, bias2);
  p4_fold<<<1025, 256, 0, stream>>>(Win, Wout, bout, bin, Fold, bout2);
  p5_init<<<512,  256, 0, stream>>>(cbuf, h0);

  kmain<<<NBLK, 512, 0, stream>>>(x, xbf, Wg, bih, bhh, W2, bias2, Fold, bout2,
                                  cbuf, h0, h1, proj, mctx, rgbuf, mem0, memT, out, barcnt);
}

// Round 4
// 14020.134 us; speedup vs baseline: 1.4087x; 1.4087x over previous
//
#include <hip/hip_runtime.h>

#define S_LEN 256
#define B_SZ  256
#define N_MEM 128
#define D_DIM 256
#define C_DIM 512
#define NBLK  256
#define AGENT __HIP_MEMORY_SCOPE_AGENT

typedef __bf16 bf16x8 __attribute__((ext_vector_type(8)));
typedef unsigned short ushort4v __attribute__((ext_vector_type(4)));
typedef float floatx4 __attribute__((ext_vector_type(4)));
typedef float floatx2 __attribute__((ext_vector_type(2)));

__device__ __forceinline__ unsigned short f2bf(float f){
  unsigned u = __float_as_uint(f);
  u += 0x7FFFu + ((u >> 16) & 1u);
  return (unsigned short)(u >> 16);
}
__device__ __forceinline__ float sigm(float x){ return 1.f/(1.f + __expf(-x)); }
__device__ __forceinline__ floatx4 mfma16(bf16x8 a, bf16x8 b, floatx4 c){
  return __builtin_amdgcn_mfma_f32_16x16x32_bf16(a, b, c, 0, 0, 0);
}

// ---- L3-coherent (agent-scope) access helpers: no cache invalidation needed ----
__device__ __forceinline__ unsigned ald32(const void* p){
  return __hip_atomic_load((const unsigned*)p, __ATOMIC_RELAXED, AGENT);
}
__device__ __forceinline__ void ast32(void* p, unsigned v){
  __hip_atomic_store((unsigned*)p, v, __ATOMIC_RELAXED, AGENT);
}
__device__ __forceinline__ void ast64(void* p, unsigned long long v){
  __hip_atomic_store((unsigned long long*)p, v, __ATOMIC_RELAXED, AGENT);
}

struct V16 { floatx4 v0,v1,v2,v3,v4,v5,v6,v7,v8,v9,v10,v11,v12,v13,v14,v15; };
#define BC(xx) __builtin_bit_cast(bf16x8, xx)

// 16 coherent 16B loads at base + kt*64B, one waitcnt. sc1 = agent scope (bypass L1/L2).
__device__ __forceinline__ V16 cload16(const unsigned short* base){
  V16 r;
  asm volatile(
    "global_load_dwordx4 %0, %16, off sc1\n\t"
    "global_load_dwordx4 %1, %16, off offset:64 sc1\n\t"
    "global_load_dwordx4 %2, %16, off offset:128 sc1\n\t"
    "global_load_dwordx4 %3, %16, off offset:192 sc1\n\t"
    "global_load_dwordx4 %4, %16, off offset:256 sc1\n\t"
    "global_load_dwordx4 %5, %16, off offset:320 sc1\n\t"
    "global_load_dwordx4 %6, %16, off offset:384 sc1\n\t"
    "global_load_dwordx4 %7, %16, off offset:448 sc1\n\t"
    "global_load_dwordx4 %8, %16, off offset:512 sc1\n\t"
    "global_load_dwordx4 %9, %16, off offset:576 sc1\n\t"
    "global_load_dwordx4 %10, %16, off offset:640 sc1\n\t"
    "global_load_dwordx4 %11, %16, off offset:704 sc1\n\t"
    "global_load_dwordx4 %12, %16, off offset:768 sc1\n\t"
    "global_load_dwordx4 %13, %16, off offset:832 sc1\n\t"
    "global_load_dwordx4 %14, %16, off offset:896 sc1\n\t"
    "global_load_dwordx4 %15, %16, off offset:960 sc1\n\t"
    "s_waitcnt vmcnt(0)"
    : "=&v"(r.v0), "=&v"(r.v1), "=&v"(r.v2), "=&v"(r.v3),
      "=&v"(r.v4), "=&v"(r.v5), "=&v"(r.v6), "=&v"(r.v7),
      "=&v"(r.v8), "=&v"(r.v9), "=&v"(r.v10), "=&v"(r.v11),
      "=&v"(r.v12), "=&v"(r.v13), "=&v"(r.v14), "=&v"(r.v15)
    : "v"(base)
    : "memory");
  __builtin_amdgcn_sched_barrier(0);   // rule #18: keep MFMAs below the waitcnt
  return r;
}

// ---------------- prologue kernels (once per call) ----------------

__global__ __launch_bounds__(256) void p0_xbf(const float* __restrict__ x,
                                              unsigned short* __restrict__ xbf){
  int idx = (blockIdx.x*256 + threadIdx.x)*4;
  floatx4 f = *(const floatx4*)(x + idx);
  ushort4v u;
  u[0]=f2bf(f[0]); u[1]=f2bf(f[1]); u[2]=f2bf(f[2]); u[3]=f2bf(f[3]);
  *(ushort4v*)(xbf + idx) = u;
}

__global__ __launch_bounds__(256) void p1_wg(const float* __restrict__ Wih,
                                             const float* __restrict__ Whh,
                                             unsigned short* __restrict__ Wg){
  int idx = blockIdx.x*256 + threadIdx.x;
  int n = idx / 768, k = idx - n*768;
  float v = (k < 256) ? Wih[n*256 + k] : Whh[n*512 + (k-256)];
  Wg[idx] = f2bf(v);
}

__global__ __launch_bounds__(256) void p2_T(const float* __restrict__ Win,
                                            const float* __restrict__ Wread,
                                            const float* __restrict__ bread,
                                            const float* __restrict__ bin,
                                            float* __restrict__ T, float* __restrict__ rq){
  if (blockIdx.x < 512){
    int idx = blockIdx.x*256 + threadIdx.x;
    int e = idx >> 9, cc = idx & 511;
    float acc = 0.f;
    for (int dp = 0; dp < 256; ++dp) acc += Win[e*256 + dp] * Wread[dp*512 + cc];
    T[idx] = acc;
  } else {
    int e = threadIdx.x;
    float acc = bin[e];
    for (int dp = 0; dp < 256; ++dp) acc += bread[dp] * Win[e*256 + dp];
    rq[e] = acc;
  }
}

__global__ __launch_bounds__(256) void p3_w2(const float* __restrict__ Win,
                                             const float* __restrict__ Wwrite,
                                             const float* __restrict__ Werase,
                                             const float* __restrict__ Wrg,
                                             const float* __restrict__ Wwg,
                                             const float* __restrict__ bwrite,
                                             const float* __restrict__ berase,
                                             const float* __restrict__ brg,
                                             const float* __restrict__ bwg,
                                             const float* __restrict__ T,
                                             const float* __restrict__ rq,
                                             unsigned short* __restrict__ W2,
                                             float* __restrict__ bias2){
  int bid = blockIdx.x;
  if (bid < 2048){
    int idx = bid*256 + threadIdx.x;
    int j = idx >> 9, cc = idx & 511;
    int h = j >> 8, d = j & 255;
    float acc = 0.f;
    const float* wk = Win + (256 + h*64)*256 + d;
    const float* tp = T + (h*64)*512 + cc;
    for (int i = 0; i < 64; ++i) acc += wk[i*256] * tp[i*512];
    W2[(size_t)j*512 + cc] = f2bf(acc);
  } else if (bid < 2048 + 1568){
    int idx = (bid - 2048)*256 + threadIdx.x;
    int r = idx >> 9, cc = idx & 511;
    float v;
    if      (r < 512) v = Wwrite[r*512 + cc];
    else if (r < 768) v = Werase[(r-512)*512 + cc];
    else if (r == 768) v = Wrg[cc];
    else if (r == 769) v = Wwg[cc];
    else v = 0.f;
    W2[(size_t)(1024 + r)*512 + cc] = f2bf(v);
  } else {
    int j = (bid - 2048 - 1568)*256 + threadIdx.x;
    if (j >= 1808) return;
    float v;
    if (j < 1024){
      int h = j >> 8, d = j & 255;
      float acc = 0.f;
      for (int i = 0; i < 64; ++i) acc += rq[h*64+i] * Win[(256 + h*64 + i)*256 + d];
      v = acc;
    }
    else if (j < 1536) v = bwrite[j - 1024];
    else if (j < 1792) v = berase[j - 1536];
    else if (j == 1792) v = brg[0];
    else if (j == 1793) v = bwg[0];
    else v = 0.f;
    bias2[j] = v;
  }
}

// Fold reindexed: column j = d*4 + h (matches mctx u64-packed d-major layout)
__global__ __launch_bounds__(256) void p4_fold(const float* __restrict__ Win,
                                               const float* __restrict__ Wout,
                                               const float* __restrict__ bout,
                                               const float* __restrict__ bin,
                                               unsigned short* __restrict__ Fold,
                                               float* __restrict__ bout2){
  if (blockIdx.x < 1024){
    int idx = blockIdx.x*256 + threadIdx.x;
    int dp = idx >> 10, j = idx & 1023;
    int h = j & 3, d = j >> 2;
    float acc = 0.f;
    const float* wv = Win + (512 + h*64)*256 + d;
    const float* wo = Wout + dp*256 + h*64;
    for (int i = 0; i < 64; ++i) acc += wv[i*256] * wo[i];
    Fold[(size_t)dp*1024 + j] = f2bf(acc);
  } else {
    int dp = threadIdx.x;
    float acc = bout[dp];
    for (int e = 0; e < 256; ++e) acc += Wout[dp*256 + e] * bin[512 + e];
    bout2[dp] = acc;
  }
}

__global__ __launch_bounds__(256) void p5_init(float* __restrict__ c,
                                               unsigned short* __restrict__ h0){
  int idx = blockIdx.x*256 + threadIdx.x;
  c[idx] = 0.f; h0[idx] = 0;
}

// ---------------- tree grid barrier: release-adds + load-only spin ----------------
// leaf[g*16] for g=0..31 (64B apart), root at leaf+512. Cumulative counts.
__device__ __forceinline__ void gbar(unsigned* leaf, unsigned* root, unsigned nb){
  __syncthreads();
  if (threadIdx.x == 0){
    const unsigned g = blockIdx.x & 31u;
    unsigned old = __hip_atomic_fetch_add(&leaf[g*16], 1u, __ATOMIC_RELEASE, AGENT);
    if (old == nb*8u - 1u)
      __hip_atomic_fetch_add(root, 1u, __ATOMIC_RELEASE, AGENT);
    while (__hip_atomic_load(root, __ATOMIC_RELAXED, AGENT) < nb*32u)
      __builtin_amdgcn_s_sleep(2);
  }
  __builtin_amdgcn_sched_barrier(0);
  __syncthreads();
}

// ---------------- persistent kernel ----------------

__device__ __forceinline__ void do_readout(int jj, int t,
                                           const unsigned short* __restrict__ mctx,
                                           const unsigned short* __restrict__ Fold,
                                           const float* __restrict__ rgl,
                                           const float* __restrict__ bout2,
                                           const float* __restrict__ x,
                                           float* __restrict__ out, int lane){
  const int mt = jj & 15, dt = jj >> 4;
  const int lm = lane & 15, lk = (lane >> 4) * 8;
  const unsigned short* ap = mctx + (size_t)(mt*16 + lm)*1024 + lk;
  const unsigned short* bp = Fold + (size_t)(dt*16 + lm)*1024 + lk;
  V16 a0 = cload16(ap);
  V16 a1 = cload16(ap + 512);
  const bf16x8 av[16] = {BC(a0.v0),BC(a0.v1),BC(a0.v2),BC(a0.v3),BC(a0.v4),BC(a0.v5),BC(a0.v6),BC(a0.v7),
                         BC(a0.v8),BC(a0.v9),BC(a0.v10),BC(a0.v11),BC(a0.v12),BC(a0.v13),BC(a0.v14),BC(a0.v15)};
  const bf16x8 bv[16] = {BC(a1.v0),BC(a1.v1),BC(a1.v2),BC(a1.v3),BC(a1.v4),BC(a1.v5),BC(a1.v6),BC(a1.v7),
                         BC(a1.v8),BC(a1.v9),BC(a1.v10),BC(a1.v11),BC(a1.v12),BC(a1.v13),BC(a1.v14),BC(a1.v15)};
  floatx4 acc = {0,0,0,0};
  #pragma unroll
  for (int kt = 0; kt < 16; ++kt)
    acc = mfma16(av[kt], *(const bf16x8*)(bp + kt*32), acc);
  #pragma unroll
  for (int kt = 0; kt < 16; ++kt)
    acc = mfma16(bv[kt], *(const bf16x8*)(bp + 512 + kt*32), acc);
  const int r0 = mt*16 + ((lane >> 4) << 2);
  const int dp = dt*16 + lm;
  const float bo = bout2[dp];
  #pragma unroll
  for (int r = 0; r < 4; ++r){
    const int bb = r0 + r;
    const size_t oi = ((size_t)bb * S_LEN + (t-1)) * D_DIM + dp;
    out[oi] = x[oi] + rgl[bb] * (acc[r] + bo);
  }
}

__global__ __launch_bounds__(512, 2) void kmain(
    const float* __restrict__ x,
    const unsigned short* __restrict__ xbf,
    const unsigned short* __restrict__ Wg,
    const float* __restrict__ bih, const float* __restrict__ bhh,
    const unsigned short* __restrict__ W2, const float* __restrict__ bias2,
    const unsigned short* __restrict__ Fold, const float* __restrict__ bout2,
    float* __restrict__ cbuf,
    unsigned short* __restrict__ h0buf, unsigned short* __restrict__ h1buf,
    float* __restrict__ proj, unsigned short* __restrict__ mctx,
    float* __restrict__ rgbuf, const float* __restrict__ mem0,
    float* __restrict__ memT, float* __restrict__ out,
    unsigned* __restrict__ barcnt)
{
  const int bid = blockIdx.x, tid = threadIdx.x;
  const int lane = tid & 63, wave = tid >> 6;
  const int lm = lane & 15, lk = (lane >> 4) * 8;

  __shared__ float memL[128][258];
  __shared__ float ga[4][16][32];
  __shared__ float qk4[4][256];
  __shared__ float wk[256], wvs[256], er[256];
  __shared__ float sc[5][512];
  __shared__ float at[5][128];

  unsigned* leaf = barcnt;
  unsigned* root = barcnt + 512;

  for (int i = tid; i < 32768; i += 512) memL[i >> 8][i & 255] = mem0[i];

  unsigned nbar = 0;
  const unsigned short* hr = h0buf;
  unsigned short* hw = h1buf;
  const int r = bid >> 4, uc = bid & 15, u0 = uc*32;
  const int g = wave >> 1, colh = wave & 1;

  for (int t = 0; t < S_LEN; ++t){
    // ---- phase AB: gates GEMM + LSTM ----
    {
      const int row = r*16 + lm;
      const unsigned short* ax = xbf + ((size_t)row*S_LEN + t)*D_DIM + lk;
      const unsigned short* ah = hr + (size_t)row*C_DIM + lk;
      const unsigned short* wb = Wg + (size_t)(g*512 + u0 + colh*16 + lm)*768 + lk;
      V16 hv = cload16(ah);                       // coherent h(t-1)
      const bf16x8 ha[16] = {BC(hv.v0),BC(hv.v1),BC(hv.v2),BC(hv.v3),BC(hv.v4),BC(hv.v5),BC(hv.v6),BC(hv.v7),
                             BC(hv.v8),BC(hv.v9),BC(hv.v10),BC(hv.v11),BC(hv.v12),BC(hv.v13),BC(hv.v14),BC(hv.v15)};
      floatx4 acc = {0,0,0,0};
      #pragma unroll
      for (int kt = 0; kt < 8; ++kt)
        acc = mfma16(*(const bf16x8*)(ax + kt*32), *(const bf16x8*)(wb + kt*32), acc);
      #pragma unroll
      for (int kt = 0; kt < 16; ++kt)
        acc = mfma16(ha[kt], *(const bf16x8*)(wb + 256 + kt*32), acc);
      const int rr0 = (lane >> 4) << 2;
      #pragma unroll
      for (int q = 0; q < 4; ++q) ga[g][rr0+q][colh*16 + lm] = acc[q];
      __syncthreads();
      if (tid < 256){
        const int ri = tid >> 4, cp = (tid & 15) * 2;
        const int b = r*16 + ri, u = u0 + cp;
        const float gi0 = ga[0][ri][cp]   + bih[u]        + bhh[u];
        const float gf0 = ga[1][ri][cp]   + bih[512 + u]  + bhh[512 + u];
        const float gg0 = ga[2][ri][cp]   + bih[1024 + u] + bhh[1024 + u];
        const float go0 = ga[3][ri][cp]   + bih[1536 + u] + bhh[1536 + u];
        const float gi1 = ga[0][ri][cp+1] + bih[u+1]        + bhh[u+1];
        const float gf1 = ga[1][ri][cp+1] + bih[512 + u+1]  + bhh[512 + u+1];
        const float gg1 = ga[2][ri][cp+1] + bih[1024 + u+1] + bhh[1024 + u+1];
        const float go1 = ga[3][ri][cp+1] + bih[1536 + u+1] + bhh[1536 + u+1];
        const int ci2 = b*512 + u;
        const float cn0 = sigm(gf0) * cbuf[ci2]   + sigm(gi0) * tanhf(gg0);
        const float cn1 = sigm(gf1) * cbuf[ci2+1] + sigm(gi1) * tanhf(gg1);
        cbuf[ci2] = cn0; cbuf[ci2+1] = cn1;
        const unsigned hv2 = (unsigned)f2bf(sigm(go0) * tanhf(cn0))
                           | ((unsigned)f2bf(sigm(go1) * tanhf(cn1)) << 16);
        ast32((unsigned*)hw + (ci2 >> 1), hv2);   // coherent h(t) store
      }
    }
    gbar(leaf, root, ++nbar);
    // ---- phase C: proj GEMM + readout(t-1) ----
    {
      float* rgl = &qk4[0][0];                    // reuse LDS (free until D)
      if (tid < 256) rgl[tid] = __uint_as_float(ald32(&rgbuf[tid]));
      __syncthreads();
      for (int jid = bid*8 + wave; jid < 2064; jid += 2048){
        if (jid < 1808){
          const int mt = jid & 15, nt = jid >> 4;
          const unsigned short* ap = hw + (size_t)(mt*16 + lm)*512 + lk;
          const unsigned short* bp = W2 + (size_t)(nt*16 + lm)*512 + lk;
          V16 av16 = cload16(ap);                 // coherent h(t)
          const bf16x8 av[16] = {BC(av16.v0),BC(av16.v1),BC(av16.v2),BC(av16.v3),BC(av16.v4),BC(av16.v5),BC(av16.v6),BC(av16.v7),
                                 BC(av16.v8),BC(av16.v9),BC(av16.v10),BC(av16.v11),BC(av16.v12),BC(av16.v13),BC(av16.v14),BC(av16.v15)};
          floatx4 acc = {0,0,0,0};
          #pragma unroll
          for (int kt = 0; kt < 16; ++kt)
            acc = mfma16(av[kt], *(const bf16x8*)(bp + kt*32), acc);
          const int r0 = mt*16 + ((lane >> 4) << 2);
          const int cc = nt*16 + lm;
          const float bv = bias2[cc];
          const bool sg = (cc >= 1536 && cc < 1794);
          #pragma unroll
          for (int q = 0; q < 4; ++q){
            float v = acc[q] + bv;
            if (sg) v = sigm(v);
            ast32(&proj[(size_t)(r0 + q)*1808 + cc], __float_as_uint(v));  // coherent
          }
        } else if (t >= 1){
          do_readout(jid - 1808, t, mctx, Fold, &qk4[0][0], bout2, x, out, lane);
        }
      }
    }
    gbar(leaf, root, ++nbar);
    // ---- phase D: attention + memory update (block = batch bid, mem in LDS) ----
    {
      const float* prow = proj + (size_t)bid * 1808;
      for (int i = tid; i < 1024; i += 512)
        qk4[i >> 8][i & 255] = __uint_as_float(ald32(&prow[i]));
      if (tid < 256){ wk[tid] = __uint_as_float(ald32(&prow[1024 + tid]));
                      er[tid] = __uint_as_float(ald32(&prow[1536 + tid])); }
      else          { wvs[tid - 256] = __uint_as_float(ald32(&prow[1280 + (tid - 256)])); }
      const float wgv = __uint_as_float(ald32(&prow[1793]));
      if (tid == 0) ast32(&rgbuf[bid], ald32(&prow[1792]));
      __syncthreads();
      {
        const int n = tid & 127, quarter = tid >> 7, db = quarter*64;
        const float* mr = &memL[n][db];
        float a0=0,a1=0,a2=0,a3=0,a4=0;
        #pragma unroll 8
        for (int i = 0; i < 64; i += 2){
          floatx2 m2 = *(const floatx2*)(mr + i);
          a0 += m2[0]*qk4[0][db+i] + m2[1]*qk4[0][db+i+1];
          a1 += m2[0]*qk4[1][db+i] + m2[1]*qk4[1][db+i+1];
          a2 += m2[0]*qk4[2][db+i] + m2[1]*qk4[2][db+i+1];
          a3 += m2[0]*qk4[3][db+i] + m2[1]*qk4[3][db+i+1];
          a4 += m2[0]*wk[db+i]     + m2[1]*wk[db+i+1];
        }
        sc[0][tid]=a0; sc[1][tid]=a1; sc[2][tid]=a2; sc[3][tid]=a3; sc[4][tid]=a4;
      }
      __syncthreads();
      if (tid < 128){
        #pragma unroll
        for (int j = 0; j < 5; ++j){
          float v = sc[j][tid] + sc[j][tid+128] + sc[j][tid+256] + sc[j][tid+384];
          sc[j][tid] = (j < 4) ? v * 0.125f : v;
        }
      }
      __syncthreads();
      {
        const int w = tid >> 6, l = tid & 63;
        if (w < 5){
          const int j = w;
          float v0 = sc[j][l], v1 = sc[j][l + 64];
          float mx = fmaxf(v0, v1);
          #pragma unroll
          for (int off = 32; off; off >>= 1) mx = fmaxf(mx, __shfl_xor(mx, off));
          float e0 = __expf(v0 - mx), e1 = __expf(v1 - mx);
          float sm = e0 + e1;
          #pragma unroll
          for (int off = 32; off; off >>= 1) sm += __shfl_xor(sm, off);
          float inv = 1.f / sm;
          at[j][l] = e0 * inv; at[j][l + 64] = e1 * inv;
        }
      }
      __syncthreads();
      if (tid < 256){
        const int d = tid;
        float m0=0,m1=0,m2=0,m3=0;
        #pragma unroll 4
        for (int n = 0; n < N_MEM; ++n){
          float m = memL[n][d];
          m0 += at[0][n] * m;
          m1 += at[1][n] * m;
          m2 += at[2][n] * m;
          m3 += at[3][n] * m;
        }
        const unsigned lo = (unsigned)f2bf(m0) | ((unsigned)f2bf(m1) << 16);
        const unsigned hi = (unsigned)f2bf(m2) | ((unsigned)f2bf(m3) << 16);
        ast64((unsigned long long*)(mctx + (size_t)bid*1024) + d,
              (unsigned long long)lo | ((unsigned long long)hi << 32));  // d-major packed
      }
      __syncthreads();
      for (int idx = tid; idx < 32768; idx += 512){
        const int n = idx >> 8, d = idx & 255;
        const float a = at[4][n];
        memL[n][d] = memL[n][d] * (1.f - a * er[d]) + wgv * (a * wvs[d]);
      }
    }
    unsigned short* tmp = (unsigned short*)hr; hr = hw; hw = tmp;
  }
  gbar(leaf, root, ++nbar);
  // final readout (t = S_LEN)
  {
    float* rgl = &qk4[0][0];
    if (tid < 256) rgl[tid] = __uint_as_float(ald32(&rgbuf[tid]));
    __syncthreads();
    const int slot = bid*8 + wave;
    if (slot < 256) do_readout(slot, S_LEN, mctx, Fold, rgl, bout2, x, out, lane);
  }
  for (int i = tid; i < 32768; i += 512)
    memT[(size_t)bid * 32768 + i] = memL[i >> 8][i & 255];
}

// ---------------- host ----------------

extern "C" void kernel_launch(void* const* d_in, const int* in_sizes, int n_in,
                              void* d_out, int out_size, void* d_ws, size_t ws_size,
                              hipStream_t stream){
  const float* x      = (const float*)d_in[0];
  const float* mem0   = (const float*)d_in[1];
  const float* Wih    = (const float*)d_in[2];
  const float* Whh    = (const float*)d_in[3];
  const float* bih    = (const float*)d_in[4];
  const float* bhh    = (const float*)d_in[5];
  const float* Wread  = (const float*)d_in[6];
  const float* bread  = (const float*)d_in[7];
  const float* Wwrite = (const float*)d_in[8];
  const float* bwrite = (const float*)d_in[9];
  const float* Werase = (const float*)d_in[10];
  const float* berase = (const float*)d_in[11];
  const float* Win    = (const float*)d_in[12];
  const float* bin    = (const float*)d_in[13];
  const float* Wout   = (const float*)d_in[14];
  const float* bout   = (const float*)d_in[15];
  const float* Wrg    = (const float*)d_in[16];
  const float* brg    = (const float*)d_in[17];
  const float* Wwg    = (const float*)d_in[18];
  const float* bwg    = (const float*)d_in[19];
  float* out = (float*)d_out;
  float* memT = out + (size_t)B_SZ * S_LEN * D_DIM;

  char* ws = (char*)d_ws;
  size_t off = 0;
  auto alloc = [&](size_t bytes) -> void* {
    void* p = ws + off; off += (bytes + 511) & ~(size_t)511; return p;
  };
  unsigned short* xbf  = (unsigned short*)alloc((size_t)B_SZ*S_LEN*D_DIM*2);
  unsigned short* Wg   = (unsigned short*)alloc((size_t)2048*768*2);
  unsigned short* W2   = (unsigned short*)alloc((size_t)1808*512*2);
  unsigned short* Fold = (unsigned short*)alloc((size_t)256*1024*2);
  float* T     = (float*)alloc((size_t)256*512*4);
  float* rq    = (float*)alloc(256*4);
  float* bias2 = (float*)alloc(1808*4);
  float* bout2 = (float*)alloc(256*4);
  float* cbuf  = (float*)alloc((size_t)256*512*4);
  unsigned short* h0 = (unsigned short*)alloc((size_t)256*512*2);
  unsigned short* h1 = (unsigned short*)alloc((size_t)256*512*2);
  float* proj  = (float*)alloc((size_t)256*1808*4);
  unsigned short* mctx = (unsigned short*)alloc((size_t)256*1024*2);
  float* rgbuf = (float*)alloc(256*4);
  unsigned* barcnt = (unsigned*)alloc(4096);
  (void)ws_size; (void)in_sizes; (void)n_in; (void)out_size;

  hipMemsetAsync(barcnt, 0, 4096, stream);
  p0_xbf <<<16384, 256, 0, stream>>>(x, xbf);
  p1_wg  <<<6144, 256, 0, stream>>>(Wih, Whh, Wg);
  p2_T   <<<513,  256, 0, stream>>>(Win, Wread, bread, bin, T, rq);
  p3_w2  <<<3624, 256, 0, stream>>>(Win, Wwrite, Werase, Wrg, Wwg, bwrite, berase, brg, bwg, T, rq, W2, bias2);
  p4_fold<<<1025, 256, 0, stream>>>(Win, Wout, bout, bin, Fold, bout2);
  p5_init<<<512,  256, 0, stream>>>(cbuf, h0);

  kmain<<<NBLK, 512, 0, stream>>>(x, xbf, Wg, bih, bhh, W2, bias2, Fold, bout2,
                                  cbuf, h0, h1, proj, mctx, rgbuf, mem0, memT, out, barcnt);
}

// Round 5
// 12410.065 us; speedup vs baseline: 1.5915x; 1.1297x over previous
//
#include <hip/hip_runtime.h>

#define S_LEN 256
#define B_SZ  256
#define N_MEM 128
#define D_DIM 256
#define C_DIM 512
#define NBLK  256
#define AGENT __HIP_MEMORY_SCOPE_AGENT

typedef __bf16 bf16x8 __attribute__((ext_vector_type(8)));
typedef unsigned short ushort4v __attribute__((ext_vector_type(4)));
typedef float floatx4 __attribute__((ext_vector_type(4)));
typedef float floatx2 __attribute__((ext_vector_type(2)));

__device__ __forceinline__ unsigned short f2bf(float f){
  unsigned u = __float_as_uint(f);
  u += 0x7FFFu + ((u >> 16) & 1u);
  return (unsigned short)(u >> 16);
}
__device__ __forceinline__ float sigm(float x){ return 1.f/(1.f + __expf(-x)); }
__device__ __forceinline__ floatx4 mfma16(bf16x8 a, bf16x8 b, floatx4 c){
  return __builtin_amdgcn_mfma_f32_16x16x32_bf16(a, b, c, 0, 0, 0);
}

// ---- L3-coherent (agent-scope, relaxed) access helpers ----
__device__ __forceinline__ unsigned ald32(const void* p){
  return __hip_atomic_load((const unsigned*)p, __ATOMIC_RELAXED, AGENT);
}
__device__ __forceinline__ void ast32(void* p, unsigned v){
  __hip_atomic_store((unsigned*)p, v, __ATOMIC_RELAXED, AGENT);
}
__device__ __forceinline__ void ast64(void* p, unsigned long long v){
  __hip_atomic_store((unsigned long long*)p, v, __ATOMIC_RELAXED, AGENT);
}

struct V16 { floatx4 v0,v1,v2,v3,v4,v5,v6,v7,v8,v9,v10,v11,v12,v13,v14,v15; };
#define BC(xx) __builtin_bit_cast(bf16x8, xx)

// 16 coherent 16B loads at base + kt*64B, one waitcnt. sc1 = agent scope (bypass L1/L2).
__device__ __forceinline__ V16 cload16(const unsigned short* base){
  V16 r;
  asm volatile(
    "global_load_dwordx4 %0, %16, off sc1\n\t"
    "global_load_dwordx4 %1, %16, off offset:64 sc1\n\t"
    "global_load_dwordx4 %2, %16, off offset:128 sc1\n\t"
    "global_load_dwordx4 %3, %16, off offset:192 sc1\n\t"
    "global_load_dwordx4 %4, %16, off offset:256 sc1\n\t"
    "global_load_dwordx4 %5, %16, off offset:320 sc1\n\t"
    "global_load_dwordx4 %6, %16, off offset:384 sc1\n\t"
    "global_load_dwordx4 %7, %16, off offset:448 sc1\n\t"
    "global_load_dwordx4 %8, %16, off offset:512 sc1\n\t"
    "global_load_dwordx4 %9, %16, off offset:576 sc1\n\t"
    "global_load_dwordx4 %10, %16, off offset:640 sc1\n\t"
    "global_load_dwordx4 %11, %16, off offset:704 sc1\n\t"
    "global_load_dwordx4 %12, %16, off offset:768 sc1\n\t"
    "global_load_dwordx4 %13, %16, off offset:832 sc1\n\t"
    "global_load_dwordx4 %14, %16, off offset:896 sc1\n\t"
    "global_load_dwordx4 %15, %16, off offset:960 sc1\n\t"
    "s_waitcnt vmcnt(0)"
    : "=&v"(r.v0), "=&v"(r.v1), "=&v"(r.v2), "=&v"(r.v3),
      "=&v"(r.v4), "=&v"(r.v5), "=&v"(r.v6), "=&v"(r.v7),
      "=&v"(r.v8), "=&v"(r.v9), "=&v"(r.v10), "=&v"(r.v11),
      "=&v"(r.v12), "=&v"(r.v13), "=&v"(r.v14), "=&v"(r.v15)
    : "v"(base)
    : "memory");
  __builtin_amdgcn_sched_barrier(0);   // rule #18: keep MFMAs below the waitcnt
  return r;
}

// ---------------- prologue kernels (once per call) ----------------

__global__ __launch_bounds__(256) void p0_xbf(const float* __restrict__ x,
                                              unsigned short* __restrict__ xbf){
  int idx = (blockIdx.x*256 + threadIdx.x)*4;
  floatx4 f = *(const floatx4*)(x + idx);
  ushort4v u;
  u[0]=f2bf(f[0]); u[1]=f2bf(f[1]); u[2]=f2bf(f[2]); u[3]=f2bf(f[3]);
  *(ushort4v*)(xbf + idx) = u;
}

__global__ __launch_bounds__(256) void p1_wg(const float* __restrict__ Wih,
                                             const float* __restrict__ Whh,
                                             unsigned short* __restrict__ Wg){
  int idx = blockIdx.x*256 + threadIdx.x;
  int n = idx / 768, k = idx - n*768;
  float v = (k < 256) ? Wih[n*256 + k] : Whh[n*512 + (k-256)];
  Wg[idx] = f2bf(v);
}

__global__ __launch_bounds__(256) void p2_T(const float* __restrict__ Win,
                                            const float* __restrict__ Wread,
                                            const float* __restrict__ bread,
                                            const float* __restrict__ bin,
                                            float* __restrict__ T, float* __restrict__ rq){
  if (blockIdx.x < 512){
    int idx = blockIdx.x*256 + threadIdx.x;
    int e = idx >> 9, cc = idx & 511;
    float acc = 0.f;
    for (int dp = 0; dp < 256; ++dp) acc += Win[e*256 + dp] * Wread[dp*512 + cc];
    T[idx] = acc;
  } else {
    int e = threadIdx.x;
    float acc = bin[e];
    for (int dp = 0; dp < 256; ++dp) acc += bread[dp] * Win[e*256 + dp];
    rq[e] = acc;
  }
}

__global__ __launch_bounds__(256) void p3_w2(const float* __restrict__ Win,
                                             const float* __restrict__ Wwrite,
                                             const float* __restrict__ Werase,
                                             const float* __restrict__ Wrg,
                                             const float* __restrict__ Wwg,
                                             const float* __restrict__ bwrite,
                                             const float* __restrict__ berase,
                                             const float* __restrict__ brg,
                                             const float* __restrict__ bwg,
                                             const float* __restrict__ T,
                                             const float* __restrict__ rq,
                                             unsigned short* __restrict__ W2,
                                             float* __restrict__ bias2){
  int bid = blockIdx.x;
  if (bid < 2048){
    int idx = bid*256 + threadIdx.x;
    int j = idx >> 9, cc = idx & 511;
    int h = j >> 8, d = j & 255;
    float acc = 0.f;
    const float* wk = Win + (256 + h*64)*256 + d;
    const float* tp = T + (h*64)*512 + cc;
    for (int i = 0; i < 64; ++i) acc += wk[i*256] * tp[i*512];
    W2[(size_t)j*512 + cc] = f2bf(acc);
  } else if (bid < 2048 + 1568){
    int idx = (bid - 2048)*256 + threadIdx.x;
    int r = idx >> 9, cc = idx & 511;
    float v;
    if      (r < 512) v = Wwrite[r*512 + cc];
    else if (r < 768) v = Werase[(r-512)*512 + cc];
    else if (r == 768) v = Wrg[cc];
    else if (r == 769) v = Wwg[cc];
    else v = 0.f;
    W2[(size_t)(1024 + r)*512 + cc] = f2bf(v);
  } else {
    int j = (bid - 2048 - 1568)*256 + threadIdx.x;
    if (j >= 1808) return;
    float v;
    if (j < 1024){
      int h = j >> 8, d = j & 255;
      float acc = 0.f;
      for (int i = 0; i < 64; ++i) acc += rq[h*64+i] * Win[(256 + h*64 + i)*256 + d];
      v = acc;
    }
    else if (j < 1536) v = bwrite[j - 1024];
    else if (j < 1792) v = berase[j - 1536];
    else if (j == 1792) v = brg[0];
    else if (j == 1793) v = bwg[0];
    else v = 0.f;
    bias2[j] = v;
  }
}

// Fold reindexed: column j = d*4 + h (matches mctx u64-packed d-major layout)
__global__ __launch_bounds__(256) void p4_fold(const float* __restrict__ Win,
                                               const float* __restrict__ Wout,
                                               const float* __restrict__ bout,
                                               const float* __restrict__ bin,
                                               unsigned short* __restrict__ Fold,
                                               float* __restrict__ bout2){
  if (blockIdx.x < 1024){
    int idx = blockIdx.x*256 + threadIdx.x;
    int dp = idx >> 10, j = idx & 1023;
    int h = j & 3, d = j >> 2;
    float acc = 0.f;
    const float* wv = Win + (512 + h*64)*256 + d;
    const float* wo = Wout + dp*256 + h*64;
    for (int i = 0; i < 64; ++i) acc += wv[i*256] * wo[i];
    Fold[(size_t)dp*1024 + j] = f2bf(acc);
  } else {
    int dp = threadIdx.x;
    float acc = bout[dp];
    for (int e = 0; e < 256; ++e) acc += Wout[dp*256 + e] * bin[512 + e];
    bout2[dp] = acc;
  }
}

__global__ __launch_bounds__(256) void p5_init(float* __restrict__ c,
                                               unsigned short* __restrict__ h0){
  int idx = blockIdx.x*256 + threadIdx.x;
  c[idx] = 0.f; h0[idx] = 0;
}

// ---------------- tree grid barrier: RELAXED adds + load-only spin ----------------
// __syncthreads() drains vmcnt(0) for every wave => all sc1 stores of this block
// are complete at the L3 coherence point BEFORE the (relaxed) arrive-add.
// No release/acquire => no buffer_wbl2 L2 writeback storms.
__device__ __forceinline__ void gbar(unsigned* leaf, unsigned* root, unsigned nb){
  __syncthreads();
  if (threadIdx.x == 0){
    const unsigned g = blockIdx.x & 31u;
    unsigned old = __hip_atomic_fetch_add(&leaf[g*16], 1u, __ATOMIC_RELAXED, AGENT);
    if (old == nb*8u - 1u)
      __hip_atomic_fetch_add(root, 1u, __ATOMIC_RELAXED, AGENT);
    while (__hip_atomic_load(root, __ATOMIC_RELAXED, AGENT) < nb*32u)
      __builtin_amdgcn_s_sleep(1);
  }
  __builtin_amdgcn_sched_barrier(0);
  __syncthreads();
}

// ---------------- persistent kernel ----------------

__device__ __forceinline__ void do_readout(int jj, int t,
                                           const unsigned short* __restrict__ mctx,
                                           const unsigned short* __restrict__ Fold,
                                           const float* __restrict__ rgl,
                                           const float* __restrict__ bout2,
                                           const float* __restrict__ x,
                                           float* __restrict__ out, int lane){
  const int mt = jj & 15, dt = jj >> 4;
  const int lm = lane & 15, lk = (lane >> 4) * 8;
  const unsigned short* ap = mctx + (size_t)(mt*16 + lm)*1024 + lk;
  const unsigned short* bp = Fold + (size_t)(dt*16 + lm)*1024 + lk;
  V16 a0 = cload16(ap);
  V16 a1 = cload16(ap + 512);
  const bf16x8 av[16] = {BC(a0.v0),BC(a0.v1),BC(a0.v2),BC(a0.v3),BC(a0.v4),BC(a0.v5),BC(a0.v6),BC(a0.v7),
                         BC(a0.v8),BC(a0.v9),BC(a0.v10),BC(a0.v11),BC(a0.v12),BC(a0.v13),BC(a0.v14),BC(a0.v15)};
  const bf16x8 bv[16] = {BC(a1.v0),BC(a1.v1),BC(a1.v2),BC(a1.v3),BC(a1.v4),BC(a1.v5),BC(a1.v6),BC(a1.v7),
                         BC(a1.v8),BC(a1.v9),BC(a1.v10),BC(a1.v11),BC(a1.v12),BC(a1.v13),BC(a1.v14),BC(a1.v15)};
  floatx4 acc = {0,0,0,0};
  #pragma unroll
  for (int kt = 0; kt < 16; ++kt)
    acc = mfma16(av[kt], *(const bf16x8*)(bp + kt*32), acc);
  #pragma unroll
  for (int kt = 0; kt < 16; ++kt)
    acc = mfma16(bv[kt], *(const bf16x8*)(bp + 512 + kt*32), acc);
  const int r0 = mt*16 + ((lane >> 4) << 2);
  const int dp = dt*16 + lm;
  const float bo = bout2[dp];
  #pragma unroll
  for (int r = 0; r < 4; ++r){
    const int bb = r0 + r;
    const size_t oi = ((size_t)bb * S_LEN + (t-1)) * D_DIM + dp;
    out[oi] = x[oi] + rgl[bb] * (acc[r] + bo);
  }
}

__global__ __launch_bounds__(512, 2) void kmain(
    const float* __restrict__ x,
    const unsigned short* __restrict__ xbf,
    const unsigned short* __restrict__ Wg,
    const float* __restrict__ bih, const float* __restrict__ bhh,
    const unsigned short* __restrict__ W2, const float* __restrict__ bias2,
    const unsigned short* __restrict__ Fold, const float* __restrict__ bout2,
    float* __restrict__ cbuf,
    unsigned short* __restrict__ h0buf, unsigned short* __restrict__ h1buf,
    float* __restrict__ proj, unsigned short* __restrict__ mctx,
    float* __restrict__ rgbuf, const float* __restrict__ mem0,
    float* __restrict__ memT, float* __restrict__ out,
    unsigned* __restrict__ barcnt)
{
  const int bid = blockIdx.x, tid = threadIdx.x;
  const int lane = tid & 63, wave = tid >> 6;
  const int lm = lane & 15, lk = (lane >> 4) * 8;

  __shared__ float memL[128][258];
  __shared__ float ga[4][16][32];
  __shared__ float qk4[4][256];
  __shared__ float wk[256], wvs[256], er[256];
  __shared__ float sc[5][512];
  __shared__ float at[5][128];

  unsigned* leaf = barcnt;
  unsigned* root = barcnt + 512;

  for (int i = tid; i < 32768; i += 512) memL[i >> 8][i & 255] = mem0[i];

  unsigned nbar = 0;
  const unsigned short* hr = h0buf;
  unsigned short* hw = h1buf;
  const int r = bid >> 4, uc = bid & 15, u0 = uc*32;
  const int g = wave >> 1, colh = wave & 1;

  for (int t = 0; t < S_LEN; ++t){
    // ---- phase AB: gates GEMM + LSTM ----
    {
      const int row = r*16 + lm;
      const unsigned short* ax = xbf + ((size_t)row*S_LEN + t)*D_DIM + lk;
      const unsigned short* ah = hr + (size_t)row*C_DIM + lk;
      const unsigned short* wb = Wg + (size_t)(g*512 + u0 + colh*16 + lm)*768 + lk;
      V16 hv = cload16(ah);                       // coherent h(t-1)
      const bf16x8 ha[16] = {BC(hv.v0),BC(hv.v1),BC(hv.v2),BC(hv.v3),BC(hv.v4),BC(hv.v5),BC(hv.v6),BC(hv.v7),
                             BC(hv.v8),BC(hv.v9),BC(hv.v10),BC(hv.v11),BC(hv.v12),BC(hv.v13),BC(hv.v14),BC(hv.v15)};
      floatx4 acc = {0,0,0,0};
      #pragma unroll
      for (int kt = 0; kt < 8; ++kt)
        acc = mfma16(*(const bf16x8*)(ax + kt*32), *(const bf16x8*)(wb + kt*32), acc);
      #pragma unroll
      for (int kt = 0; kt < 16; ++kt)
        acc = mfma16(ha[kt], *(const bf16x8*)(wb + 256 + kt*32), acc);
      const int rr0 = (lane >> 4) << 2;
      #pragma unroll
      for (int q = 0; q < 4; ++q) ga[g][rr0+q][colh*16 + lm] = acc[q];
      __syncthreads();
      if (tid < 256){
        const int ri = tid >> 4, cp = (tid & 15) * 2;
        const int b = r*16 + ri, u = u0 + cp;
        const float gi0 = ga[0][ri][cp]   + bih[u]        + bhh[u];
        const float gf0 = ga[1][ri][cp]   + bih[512 + u]  + bhh[512 + u];
        const float gg0 = ga[2][ri][cp]   + bih[1024 + u] + bhh[1024 + u];
        const float go0 = ga[3][ri][cp]   + bih[1536 + u] + bhh[1536 + u];
        const float gi1 = ga[0][ri][cp+1] + bih[u+1]        + bhh[u+1];
        const float gf1 = ga[1][ri][cp+1] + bih[512 + u+1]  + bhh[512 + u+1];
        const float gg1 = ga[2][ri][cp+1] + bih[1024 + u+1] + bhh[1024 + u+1];
        const float go1 = ga[3][ri][cp+1] + bih[1536 + u+1] + bhh[1536 + u+1];
        const int ci2 = b*512 + u;
        const float cn0 = sigm(gf0) * cbuf[ci2]   + sigm(gi0) * tanhf(gg0);
        const float cn1 = sigm(gf1) * cbuf[ci2+1] + sigm(gi1) * tanhf(gg1);
        cbuf[ci2] = cn0; cbuf[ci2+1] = cn1;
        const unsigned hv2 = (unsigned)f2bf(sigm(go0) * tanhf(cn0))
                           | ((unsigned)f2bf(sigm(go1) * tanhf(cn1)) << 16);
        ast32((unsigned*)hw + (ci2 >> 1), hv2);   // coherent h(t) store
      }
    }
    gbar(leaf, root, ++nbar);
    // ---- phase C: proj GEMM + readout(t-1) ----
    {
      float* rgl = &qk4[0][0];                    // reuse LDS (free until D)
      if (tid < 256) rgl[tid] = __uint_as_float(ald32(&rgbuf[tid]));
      __syncthreads();
      for (int jid = bid*8 + wave; jid < 2064; jid += 2048){
        if (jid < 1808){
          const int mt = jid & 15, nt = jid >> 4;
          const unsigned short* ap = hw + (size_t)(mt*16 + lm)*512 + lk;
          const unsigned short* bp = W2 + (size_t)(nt*16 + lm)*512 + lk;
          V16 av16 = cload16(ap);                 // coherent h(t)
          const bf16x8 av[16] = {BC(av16.v0),BC(av16.v1),BC(av16.v2),BC(av16.v3),BC(av16.v4),BC(av16.v5),BC(av16.v6),BC(av16.v7),
                                 BC(av16.v8),BC(av16.v9),BC(av16.v10),BC(av16.v11),BC(av16.v12),BC(av16.v13),BC(av16.v14),BC(av16.v15)};
          floatx4 acc = {0,0,0,0};
          #pragma unroll
          for (int kt = 0; kt < 16; ++kt)
            acc = mfma16(av[kt], *(const bf16x8*)(bp + kt*32), acc);
          const int r0 = mt*16 + ((lane >> 4) << 2);
          const int cc = nt*16 + lm;
          const float bv = bias2[cc];
          const bool sg = (cc >= 1536 && cc < 1794);
          #pragma unroll
          for (int q = 0; q < 4; ++q){
            float v = acc[q] + bv;
            if (sg) v = sigm(v);
            ast32(&proj[(size_t)(r0 + q)*1808 + cc], __float_as_uint(v));  // coherent
          }
        } else if (t >= 1){
          do_readout(jid - 1808, t, mctx, Fold, &qk4[0][0], bout2, x, out, lane);
        }
      }
    }
    gbar(leaf, root, ++nbar);
    // ---- phase D: attention + memory update (block = batch bid, mem in LDS) ----
    {
      const float* prow = proj + (size_t)bid * 1808;
      for (int i = tid; i < 1024; i += 512)
        qk4[i >> 8][i & 255] = __uint_as_float(ald32(&prow[i]));
      if (tid < 256){ wk[tid] = __uint_as_float(ald32(&prow[1024 + tid]));
                      er[tid] = __uint_as_float(ald32(&prow[1536 + tid])); }
      else          { wvs[tid - 256] = __uint_as_float(ald32(&prow[1280 + (tid - 256)])); }
      const float wgv = __uint_as_float(ald32(&prow[1793]));
      if (tid == 0) ast32(&rgbuf[bid], ald32(&prow[1792]));
      __syncthreads();
      {
        const int n = tid & 127, quarter = tid >> 7, db = quarter*64;
        const float* mr = &memL[n][db];
        float a0=0,a1=0,a2=0,a3=0,a4=0;
        #pragma unroll 8
        for (int i = 0; i < 64; i += 2){
          floatx2 m2 = *(const floatx2*)(mr + i);
          a0 += m2[0]*qk4[0][db+i] + m2[1]*qk4[0][db+i+1];
          a1 += m2[0]*qk4[1][db+i] + m2[1]*qk4[1][db+i+1];
          a2 += m2[0]*qk4[2][db+i] + m2[1]*qk4[2][db+i+1];
          a3 += m2[0]*qk4[3][db+i] + m2[1]*qk4[3][db+i+1];
          a4 += m2[0]*wk[db+i]     + m2[1]*wk[db+i+1];
        }
        sc[0][tid]=a0; sc[1][tid]=a1; sc[2][tid]=a2; sc[3][tid]=a3; sc[4][tid]=a4;
      }
      __syncthreads();
      if (tid < 128){
        #pragma unroll
        for (int j = 0; j < 5; ++j){
          float v = sc[j][tid] + sc[j][tid+128] + sc[j][tid+256] + sc[j][tid+384];
          sc[j][tid] = (j < 4) ? v * 0.125f : v;
        }
      }
      __syncthreads();
      {
        const int w = tid >> 6, l = tid & 63;
        if (w < 5){
          const int j = w;
          float v0 = sc[j][l], v1 = sc[j][l + 64];
          float mx = fmaxf(v0, v1);
          #pragma unroll
          for (int off = 32; off; off >>= 1) mx = fmaxf(mx, __shfl_xor(mx, off));
          float e0 = __expf(v0 - mx), e1 = __expf(v1 - mx);
          float sm = e0 + e1;
          #pragma unroll
          for (int off = 32; off; off >>= 1) sm += __shfl_xor(sm, off);
          float inv = 1.f / sm;
          at[j][l] = e0 * inv; at[j][l + 64] = e1 * inv;
        }
      }
      __syncthreads();
      if (tid < 256){
        const int d = tid;
        float m0=0,m1=0,m2=0,m3=0;
        #pragma unroll 4
        for (int n = 0; n < N_MEM; ++n){
          float m = memL[n][d];
          m0 += at[0][n] * m;
          m1 += at[1][n] * m;
          m2 += at[2][n] * m;
          m3 += at[3][n] * m;
        }
        const unsigned lo = (unsigned)f2bf(m0) | ((unsigned)f2bf(m1) << 16);
        const unsigned hi = (unsigned)f2bf(m2) | ((unsigned)f2bf(m3) << 16);
        ast64((unsigned long long*)(mctx + (size_t)bid*1024) + d,
              (unsigned long long)lo | ((unsigned long long)hi << 32));  // d-major packed
      }
      __syncthreads();
      for (int idx = tid; idx < 32768; idx += 512){
        const int n = idx >> 8, d = idx & 255;
        const float a = at[4][n];
        memL[n][d] = memL[n][d] * (1.f - a * er[d]) + wgv * (a * wvs[d]);
      }
    }
    unsigned short* tmp = (unsigned short*)hr; hr = hw; hw = tmp;
  }
  gbar(leaf, root, ++nbar);
  // final readout (t = S_LEN)
  {
    float* rgl = &qk4[0][0];
    if (tid < 256) rgl[tid] = __uint_as_float(ald32(&rgbuf[tid]));
    __syncthreads();
    const int slot = bid*8 + wave;
    if (slot < 256) do_readout(slot, S_LEN, mctx, Fold, rgl, bout2, x, out, lane);
  }
  for (int i = tid; i < 32768; i += 512)
    memT[(size_t)bid * 32768 + i] = memL[i >> 8][i & 255];
}

// ---------------- host ----------------

extern "C" void kernel_launch(void* const* d_in, const int* in_sizes, int n_in,
                              void* d_out, int out_size, void* d_ws, size_t ws_size,
                              hipStream_t stream){
  const float* x      = (const float*)d_in[0];
  const float* mem0   = (const float*)d_in[1];
  const float* Wih    = (const float*)d_in[2];
  const float* Whh    = (const float*)d_in[3];
  const float* bih    = (const float*)d_in[4];
  const float* bhh    = (const float*)d_in[5];
  const float* Wread  = (const float*)d_in[6];
  const float* bread  = (const float*)d_in[7];
  const float* Wwrite = (const float*)d_in[8];
  const float* bwrite = (const float*)d_in[9];
  const float* Werase = (const float*)d_in[10];
  const float* berase = (const float*)d_in[11];
  const float* Win    = (const float*)d_in[12];
  const float* bin    = (const float*)d_in[13];
  const float* Wout   = (const float*)d_in[14];
  const float* bout   = (const float*)d_in[15];
  const float* Wrg    = (const float*)d_in[16];
  const float* brg    = (const float*)d_in[17];
  const float* Wwg    = (const float*)d_in[18];
  const float* bwg    = (const float*)d_in[19];
  float* out = (float*)d_out;
  float* memT = out + (size_t)B_SZ * S_LEN * D_DIM;

  char* ws = (char*)d_ws;
  size_t off = 0;
  auto alloc = [&](size_t bytes) -> void* {
    void* p = ws + off; off += (bytes + 511) & ~(size_t)511; return p;
  };
  unsigned short* xbf  = (unsigned short*)alloc((size_t)B_SZ*S_LEN*D_DIM*2);
  unsigned short* Wg   = (unsigned short*)alloc((size_t)2048*768*2);
  unsigned short* W2   = (unsigned short*)alloc((size_t)1808*512*2);
  unsigned short* Fold = (unsigned short*)alloc((size_t)256*1024*2);
  float* T     = (float*)alloc((size_t)256*512*4);
  float* rq    = (float*)alloc(256*4);
  float* bias2 = (float*)alloc(1808*4);
  float* bout2 = (float*)alloc(256*4);
  float* cbuf  = (float*)alloc((size_t)256*512*4);
  unsigned short* h0 = (unsigned short*)alloc((size_t)256*512*2);
  unsigned short* h1 = (unsigned short*)alloc((size_t)256*512*2);
  float* proj  = (float*)alloc((size_t)256*1808*4);
  unsigned short* mctx = (unsigned short*)alloc((size_t)256*1024*2);
  float* rgbuf = (float*)alloc(256*4);
  unsigned* barcnt = (unsigned*)alloc(4096);
  (void)ws_size; (void)in_sizes; (void)n_in; (void)out_size;

  hipMemsetAsync(barcnt, 0, 4096, stream);
  p0_xbf <<<16384, 256, 0, stream>>>(x, xbf);
  p1_wg  <<<6144, 256, 0, stream>>>(Wih, Whh, Wg);
  p2_T   <<<513,  256, 0, stream>>>(Win, Wread, bread, bin, T, rq);
  p3_w2  <<<3624, 256, 0, stream>>>(Win, Wwrite, Werase, Wrg, Wwg, bwrite, berase, brg, bwg, T, rq, W2, bias2);
  p4_fold<<<1025, 256, 0, stream>>>(Win, Wout, bout, bin, Fold, bout2);
  p5_init<<<512,  256, 0, stream>>>(cbuf, h0);

  kmain<<<NBLK, 512, 0, stream>>>(x, xbf, Wg, bih, bhh, W2, bias2, Fold, bout2,
                                  cbuf, h0, h1, proj, mctx, rgbuf, mem0, memT, out, barcnt);
}

// Round 7
// 11374.373 us; speedup vs baseline: 1.7364x; 1.0911x over previous
//
#include <hip/hip_runtime.h>

#define S_LEN 256
#define B_SZ  256
#define N_MEM 128
#define D_DIM 256
#define C_DIM 512
#define NBLK  256
#define MSTR  260   // memL row stride (f32): 16B-aligned rows, b128 conflict-free
#define AGENT __HIP_MEMORY_SCOPE_AGENT

typedef __bf16 bf16x8 __attribute__((ext_vector_type(8)));
typedef unsigned short ushort4v __attribute__((ext_vector_type(4)));
typedef float floatx4 __attribute__((ext_vector_type(4)));
typedef float floatx2 __attribute__((ext_vector_type(2)));

__device__ __forceinline__ unsigned short f2bf(float f){
  unsigned u = __float_as_uint(f);
  u += 0x7FFFu + ((u >> 16) & 1u);
  return (unsigned short)(u >> 16);
}
__device__ __forceinline__ float bf2f(unsigned short v){
  return __uint_as_float(((unsigned)v) << 16);
}
__device__ __forceinline__ float sigm(float x){ return 1.f/(1.f + __expf(-x)); }
__device__ __forceinline__ floatx4 mfma16(bf16x8 a, bf16x8 b, floatx4 c){
  return __builtin_amdgcn_mfma_f32_16x16x32_bf16(a, b, c, 0, 0, 0);
}

// ---- L3-coherent (agent-scope, relaxed) helpers ----
__device__ __forceinline__ unsigned ald32(const void* p){
  return __hip_atomic_load((const unsigned*)p, __ATOMIC_RELAXED, AGENT);
}
__device__ __forceinline__ void ast32(void* p, unsigned v){
  __hip_atomic_store((unsigned*)p, v, __ATOMIC_RELAXED, AGENT);
}
__device__ __forceinline__ void ast64(void* p, unsigned long long v){
  __hip_atomic_store((unsigned long long*)p, v, __ATOMIC_RELAXED, AGENT);
}
__device__ __forceinline__ void sst16(void* p, unsigned short v){
  asm volatile("global_store_short %0, %1, off sc1" :: "v"(p), "v"(v) : "memory");
}

struct V16 { floatx4 v0,v1,v2,v3,v4,v5,v6,v7,v8,v9,v10,v11,v12,v13,v14,v15; };
#define BC(xx) __builtin_bit_cast(bf16x8, xx)

// blocking variant: 16 coherent 16B loads + wait (phase C / readout)
__device__ __forceinline__ V16 cload16(const unsigned short* base){
  V16 r;
  asm volatile(
    "global_load_dwordx4 %0, %16, off sc1\n\t"
    "global_load_dwordx4 %1, %16, off offset:64 sc1\n\t"
    "global_load_dwordx4 %2, %16, off offset:128 sc1\n\t"
    "global_load_dwordx4 %3, %16, off offset:192 sc1\n\t"
    "global_load_dwordx4 %4, %16, off offset:256 sc1\n\t"
    "global_load_dwordx4 %5, %16, off offset:320 sc1\n\t"
    "global_load_dwordx4 %6, %16, off offset:384 sc1\n\t"
    "global_load_dwordx4 %7, %16, off offset:448 sc1\n\t"
    "global_load_dwordx4 %8, %16, off offset:512 sc1\n\t"
    "global_load_dwordx4 %9, %16, off offset:576 sc1\n\t"
    "global_load_dwordx4 %10, %16, off offset:640 sc1\n\t"
    "global_load_dwordx4 %11, %16, off offset:704 sc1\n\t"
    "global_load_dwordx4 %12, %16, off offset:768 sc1\n\t"
    "global_load_dwordx4 %13, %16, off offset:832 sc1\n\t"
    "global_load_dwordx4 %14, %16, off offset:896 sc1\n\t"
    "global_load_dwordx4 %15, %16, off offset:960 sc1\n\t"
    "s_waitcnt vmcnt(0)"
    : "=&v"(r.v0), "=&v"(r.v1), "=&v"(r.v2), "=&v"(r.v3),
      "=&v"(r.v4), "=&v"(r.v5), "=&v"(r.v6), "=&v"(r.v7),
      "=&v"(r.v8), "=&v"(r.v9), "=&v"(r.v10), "=&v"(r.v11),
      "=&v"(r.v12), "=&v"(r.v13), "=&v"(r.v14), "=&v"(r.v15)
    : "v"(base)
    : "memory");
  __builtin_amdgcn_sched_barrier(0);
  return r;
}

// split variant: issue now (no wait), wait later via cwait16
__device__ __forceinline__ void cload16_issue(const unsigned short* base, floatx4 r[16]){
  asm volatile(
    "global_load_dwordx4 %0, %16, off sc1\n\t"
    "global_load_dwordx4 %1, %16, off offset:64 sc1\n\t"
    "global_load_dwordx4 %2, %16, off offset:128 sc1\n\t"
    "global_load_dwordx4 %3, %16, off offset:192 sc1\n\t"
    "global_load_dwordx4 %4, %16, off offset:256 sc1\n\t"
    "global_load_dwordx4 %5, %16, off offset:320 sc1\n\t"
    "global_load_dwordx4 %6, %16, off offset:384 sc1\n\t"
    "global_load_dwordx4 %7, %16, off offset:448 sc1\n\t"
    "global_load_dwordx4 %8, %16, off offset:512 sc1\n\t"
    "global_load_dwordx4 %9, %16, off offset:576 sc1\n\t"
    "global_load_dwordx4 %10, %16, off offset:640 sc1\n\t"
    "global_load_dwordx4 %11, %16, off offset:704 sc1\n\t"
    "global_load_dwordx4 %12, %16, off offset:768 sc1\n\t"
    "global_load_dwordx4 %13, %16, off offset:832 sc1\n\t"
    "global_load_dwordx4 %14, %16, off offset:896 sc1\n\t"
    "global_load_dwordx4 %15, %16, off offset:960 sc1"
    : "=&v"(r[0]), "=&v"(r[1]), "=&v"(r[2]), "=&v"(r[3]),
      "=&v"(r[4]), "=&v"(r[5]), "=&v"(r[6]), "=&v"(r[7]),
      "=&v"(r[8]), "=&v"(r[9]), "=&v"(r[10]), "=&v"(r[11]),
      "=&v"(r[12]), "=&v"(r[13]), "=&v"(r[14]), "=&v"(r[15])
    : "v"(base)
    : "memory");
}
__device__ __forceinline__ void cwait16(floatx4 r[16]){
  asm volatile("s_waitcnt vmcnt(0)"
    : "+v"(r[0]), "+v"(r[1]), "+v"(r[2]), "+v"(r[3]),
      "+v"(r[4]), "+v"(r[5]), "+v"(r[6]), "+v"(r[7]),
      "+v"(r[8]), "+v"(r[9]), "+v"(r[10]), "+v"(r[11]),
      "+v"(r[12]), "+v"(r[13]), "+v"(r[14]), "+v"(r[15])
    :: "memory");
  __builtin_amdgcn_sched_barrier(0);
}

// ---------------- prologue kernels ----------------

__global__ __launch_bounds__(256) void p0_xbf(const float* __restrict__ x,
                                              unsigned short* __restrict__ xbf){
  int idx = (blockIdx.x*256 + threadIdx.x)*4;
  floatx4 f = *(const floatx4*)(x + idx);
  ushort4v u;
  u[0]=f2bf(f[0]); u[1]=f2bf(f[1]); u[2]=f2bf(f[2]); u[3]=f2bf(f[3]);
  *(ushort4v*)(xbf + idx) = u;
}

__global__ __launch_bounds__(256) void p1_wg(const float* __restrict__ Wih,
                                             const float* __restrict__ Whh,
                                             unsigned short* __restrict__ Wg){
  int idx = blockIdx.x*256 + threadIdx.x;
  int n = idx / 768, k = idx - n*768;
  float v = (k < 256) ? Wih[n*256 + k] : Whh[n*512 + (k-256)];
  Wg[idx] = f2bf(v);
}

__global__ __launch_bounds__(256) void p2_T(const float* __restrict__ Win,
                                            const float* __restrict__ Wread,
                                            const float* __restrict__ bread,
                                            const float* __restrict__ bin,
                                            float* __restrict__ T, float* __restrict__ rq){
  if (blockIdx.x < 512){
    int idx = blockIdx.x*256 + threadIdx.x;
    int e = idx >> 9, cc = idx & 511;
    float acc = 0.f;
    for (int dp = 0; dp < 256; ++dp) acc += Win[e*256 + dp] * Wread[dp*512 + cc];
    T[idx] = acc;
  } else {
    int e = threadIdx.x;
    float acc = bin[e];
    for (int dp = 0; dp < 256; ++dp) acc += bread[dp] * Win[e*256 + dp];
    rq[e] = acc;
  }
}

__global__ __launch_bounds__(256) void p3_w2(const float* __restrict__ Win,
                                             const float* __restrict__ Wwrite,
                                             const float* __restrict__ Werase,
                                             const float* __restrict__ Wrg,
                                             const float* __restrict__ Wwg,
                                             const float* __restrict__ bwrite,
                                             const float* __restrict__ berase,
                                             const float* __restrict__ brg,
                                             const float* __restrict__ bwg,
                                             const float* __restrict__ T,
                                             const float* __restrict__ rq,
                                             unsigned short* __restrict__ W2,
                                             float* __restrict__ bias2){
  int bid = blockIdx.x;
  if (bid < 2048){
    int idx = bid*256 + threadIdx.x;
    int j = idx >> 9, cc = idx & 511;
    int h = j >> 8, d = j & 255;
    float acc = 0.f;
    const float* wk = Win + (256 + h*64)*256 + d;
    const float* tp = T + (h*64)*512 + cc;
    for (int i = 0; i < 64; ++i) acc += wk[i*256] * tp[i*512];
    W2[(size_t)j*512 + cc] = f2bf(acc);
  } else if (bid < 2048 + 1568){
    int idx = (bid - 2048)*256 + threadIdx.x;
    int r = idx >> 9, cc = idx & 511;
    float v;
    if      (r < 512) v = Wwrite[r*512 + cc];
    else if (r < 768) v = Werase[(r-512)*512 + cc];
    else if (r == 768) v = Wrg[cc];
    else if (r == 769) v = Wwg[cc];
    else v = 0.f;
    W2[(size_t)(1024 + r)*512 + cc] = f2bf(v);
  } else {
    int j = (bid - 2048 - 1568)*256 + threadIdx.x;
    if (j >= 1808) return;
    float v;
    if (j < 1024){
      int h = j >> 8, d = j & 255;
      float acc = 0.f;
      for (int i = 0; i < 64; ++i) acc += rq[h*64+i] * Win[(256 + h*64 + i)*256 + d];
      v = acc;
    }
    else if (j < 1536) v = bwrite[j - 1024];
    else if (j < 1792) v = berase[j - 1536];
    else if (j == 1792) v = brg[0];
    else if (j == 1793) v = bwg[0];
    else v = 0.f;
    bias2[j] = v;
  }
}

// Fold: column j = d*4 + h (matches mctx u64-packed d-major layout)
__global__ __launch_bounds__(256) void p4_fold(const float* __restrict__ Win,
                                               const float* __restrict__ Wout,
                                               const float* __restrict__ bout,
                                               const float* __restrict__ bin,
                                               unsigned short* __restrict__ Fold,
                                               float* __restrict__ bout2){
  if (blockIdx.x < 1024){
    int idx = blockIdx.x*256 + threadIdx.x;
    int dp = idx >> 10, j = idx & 1023;
    int h = j & 3, d = j >> 2;
    float acc = 0.f;
    const float* wv = Win + (512 + h*64)*256 + d;
    const float* wo = Wout + dp*256 + h*64;
    for (int i = 0; i < 64; ++i) acc += wv[i*256] * wo[i];
    Fold[(size_t)dp*1024 + j] = f2bf(acc);
  } else {
    int dp = threadIdx.x;
    float acc = bout[dp];
    for (int e = 0; e < 256; ++e) acc += Wout[dp*256 + e] * bin[512 + e];
    bout2[dp] = acc;
  }
}

// zero c/h0, biasg = bih + bhh
__global__ __launch_bounds__(256) void p5_init(const float* __restrict__ bih,
                                               const float* __restrict__ bhh,
                                               float* __restrict__ biasg,
                                               float* __restrict__ c,
                                               unsigned short* __restrict__ h0){
  int idx = blockIdx.x*256 + threadIdx.x;
  c[idx] = 0.f; h0[idx] = 0;
  if (idx < 2048) biasg[idx] = bih[idx] + bhh[idx];
}

// ---------------- tree grid barrier (relaxed, proven R5) ----------------
__device__ __forceinline__ void gbar(unsigned* leaf, unsigned* root, unsigned nb){
  __syncthreads();
  if (threadIdx.x == 0){
    const unsigned g = blockIdx.x & 31u;
    unsigned old = __hip_atomic_fetch_add(&leaf[g*16], 1u, __ATOMIC_RELAXED, AGENT);
    if (old == nb*8u - 1u)
      __hip_atomic_fetch_add(root, 1u, __ATOMIC_RELAXED, AGENT);
    while (__hip_atomic_load(root, __ATOMIC_RELAXED, AGENT) < nb*32u)
      __builtin_amdgcn_s_sleep(1);
  }
  __builtin_amdgcn_sched_barrier(0);
  __syncthreads();
}

// ---------------- persistent kernel ----------------

__device__ __forceinline__ void do_readout(int jj, int t,
                                           const unsigned short* __restrict__ mctx,
                                           const unsigned short* __restrict__ Fold,
                                           const float* __restrict__ rgl,
                                           const float* __restrict__ bout2,
                                           const float* __restrict__ x,
                                           float* __restrict__ out, int lane){
  const int mt = jj & 15, dt = jj >> 4;
  const int lm = lane & 15, lk = (lane >> 4) * 8;
  const unsigned short* ap = mctx + (size_t)(mt*16 + lm)*1024 + lk;
  const unsigned short* bp = Fold + (size_t)(dt*16 + lm)*1024 + lk;
  V16 a0 = cload16(ap);
  V16 a1 = cload16(ap + 512);
  const bf16x8 av[16] = {BC(a0.v0),BC(a0.v1),BC(a0.v2),BC(a0.v3),BC(a0.v4),BC(a0.v5),BC(a0.v6),BC(a0.v7),
                         BC(a0.v8),BC(a0.v9),BC(a0.v10),BC(a0.v11),BC(a0.v12),BC(a0.v13),BC(a0.v14),BC(a0.v15)};
  const bf16x8 bv[16] = {BC(a1.v0),BC(a1.v1),BC(a1.v2),BC(a1.v3),BC(a1.v4),BC(a1.v5),BC(a1.v6),BC(a1.v7),
                         BC(a1.v8),BC(a1.v9),BC(a1.v10),BC(a1.v11),BC(a1.v12),BC(a1.v13),BC(a1.v14),BC(a1.v15)};
  floatx4 acc = {0,0,0,0};
  #pragma unroll
  for (int kt = 0; kt < 16; ++kt)
    acc = mfma16(av[kt], *(const bf16x8*)(bp + kt*32), acc);
  #pragma unroll
  for (int kt = 0; kt < 16; ++kt)
    acc = mfma16(bv[kt], *(const bf16x8*)(bp + 512 + kt*32), acc);
  const int r0 = mt*16 + ((lane >> 4) << 2);
  const int dp = dt*16 + lm;
  const float bo = bout2[dp];
  #pragma unroll
  for (int r = 0; r < 4; ++r){
    const int bb = r0 + r;
    const size_t oi = ((size_t)bb * S_LEN + (t-1)) * D_DIM + dp;
    out[oi] = x[oi] + rgl[bb] * (acc[r] + bo);
  }
}

__global__ __launch_bounds__(512, 2) void kmain(
    const float* __restrict__ x,
    const unsigned short* __restrict__ xbf,
    const unsigned short* __restrict__ Wg,
    const float* __restrict__ biasg,
    const unsigned short* __restrict__ W2, const float* __restrict__ bias2,
    const unsigned short* __restrict__ Fold, const float* __restrict__ bout2,
    float* __restrict__ cbuf,
    unsigned short* __restrict__ h0buf, unsigned short* __restrict__ h1buf,
    unsigned short* __restrict__ projB, unsigned short* __restrict__ mctx,
    float* __restrict__ rgbuf, const float* __restrict__ mem0,
    float* __restrict__ memT, float* __restrict__ out,
    unsigned* __restrict__ barcnt)
{
  const int bid = blockIdx.x, tid = threadIdx.x;
  const int lane = tid & 63, wave = tid >> 6;
  const int lm = lane & 15, lk = (lane >> 4) * 8;

  __shared__ float memL[128][MSTR];   // 133120 B (persistent)
  __shared__ float scU[5][512];       //  10240 B (AB: ga / D: scores,mctx-partial)
  __shared__ float qkW[5][256];       //   5120 B
  __shared__ float er[256];           //   1024 B (D: erase / C: rgl)
  __shared__ float wvs[256];          //   1024 B
  __shared__ float attT[128][8];      //   4096 B
  __shared__ float wgS;
  float (*ga)[16][32] = (float (*)[16][32])&scU[0][0];
  floatx4* mpart = (floatx4*)&scU[0][0];

  unsigned* leaf = barcnt;
  unsigned* root = barcnt + 512;

  for (int i = tid; i < 32768; i += 512) memL[i >> 8][i & 255] = mem0[i];

  unsigned nbar = 0;
  const unsigned short* hr = h0buf;
  unsigned short* hw = h1buf;
  const int r = bid >> 4, uc = bid & 15, u0 = uc*32;
  const int g = wave >> 1, colh = wave & 1;
  const int row = r*16 + lm;

  // prologue prefetch: h(-1)=0 buffer + x(0)
  floatx4 hq[16];
  bf16x8 xfr[8];
  cload16_issue(hr + (size_t)row*C_DIM + lk, hq);
  {
    const unsigned short* ax = xbf + ((size_t)row*S_LEN + 0)*D_DIM + lk;
    #pragma unroll
    for (int kt = 0; kt < 8; ++kt) xfr[kt] = *(const bf16x8*)(ax + kt*32);
  }

  for (int t = 0; t < S_LEN; ++t){
    // ---- phase AB: gates GEMM + LSTM ----
    {
      const unsigned short* wb = Wg + (size_t)(g*512 + u0 + colh*16 + lm)*768 + lk;
      cwait16(hq);                         // h(t-1) prefetched during D(t-1)
      floatx4 acc = {0,0,0,0};
      #pragma unroll
      for (int kt = 0; kt < 8; ++kt)
        acc = mfma16(xfr[kt], *(const bf16x8*)(wb + kt*32), acc);
      #pragma unroll
      for (int kt = 0; kt < 16; ++kt)
        acc = mfma16(BC(hq[kt]), *(const bf16x8*)(wb + 256 + kt*32), acc);
      const int rr0 = (lane >> 4) << 2;
      #pragma unroll
      for (int q = 0; q < 4; ++q) ga[g][rr0+q][colh*16 + lm] = acc[q];
      __syncthreads();
      if (tid < 256){
        const int ri = tid >> 4, cp = (tid & 15) * 2;
        const int b = r*16 + ri, u = u0 + cp;
        floatx2 bg0 = *(const floatx2*)&biasg[u];
        floatx2 bg1 = *(const floatx2*)&biasg[512 + u];
        floatx2 bg2 = *(const floatx2*)&biasg[1024 + u];
        floatx2 bg3 = *(const floatx2*)&biasg[1536 + u];
        const float gi0 = ga[0][ri][cp]   + bg0[0];
        const float gf0 = ga[1][ri][cp]   + bg1[0];
        const float gg0 = ga[2][ri][cp]   + bg2[0];
        const float go0 = ga[3][ri][cp]   + bg3[0];
        const float gi1 = ga[0][ri][cp+1] + bg0[1];
        const float gf1 = ga[1][ri][cp+1] + bg1[1];
        const float gg1 = ga[2][ri][cp+1] + bg2[1];
        const float go1 = ga[3][ri][cp+1] + bg3[1];
        const int ci2 = b*512 + u;
        floatx2 cv = *(const floatx2*)&cbuf[ci2];
        const float cn0 = sigm(gf0) * cv[0] + sigm(gi0) * tanhf(gg0);
        const float cn1 = sigm(gf1) * cv[1] + sigm(gi1) * tanhf(gg1);
        floatx2 cw; cw[0] = cn0; cw[1] = cn1;
        *(floatx2*)&cbuf[ci2] = cw;
        const unsigned hv2 = (unsigned)f2bf(sigm(go0) * tanhf(cn0))
                           | ((unsigned)f2bf(sigm(go1) * tanhf(cn1)) << 16);
        ast32((unsigned*)hw + (ci2 >> 1), hv2);
      }
    }
    gbar(leaf, root, ++nbar);
    // ---- phase C: proj GEMM (bf16 out) + readout(t-1) ----
    {
      if (tid < 256) er[tid] = __uint_as_float(ald32(&rgbuf[((t-1)&1)*256 + tid]));
      __syncthreads();
      float* rgcur = rgbuf + (t&1)*256;
      for (int jid = bid*8 + wave; jid < 2064; jid += 2048){
        if (jid < 1808){
          const int mt = jid & 15, nt = jid >> 4;
          const unsigned short* ap = hw + (size_t)(mt*16 + lm)*512 + lk;
          const unsigned short* bp = W2 + (size_t)(nt*16 + lm)*512 + lk;
          V16 av16 = cload16(ap);
          const bf16x8 av[16] = {BC(av16.v0),BC(av16.v1),BC(av16.v2),BC(av16.v3),BC(av16.v4),BC(av16.v5),BC(av16.v6),BC(av16.v7),
                                 BC(av16.v8),BC(av16.v9),BC(av16.v10),BC(av16.v11),BC(av16.v12),BC(av16.v13),BC(av16.v14),BC(av16.v15)};
          floatx4 acc = {0,0,0,0};
          #pragma unroll
          for (int kt = 0; kt < 16; ++kt)
            acc = mfma16(av[kt], *(const bf16x8*)(bp + kt*32), acc);
          const int r0 = mt*16 + ((lane >> 4) << 2);
          const int cc = nt*16 + lm;
          const float bv = bias2[cc];
          const bool sg = (cc >= 1536 && cc < 1794);
          #pragma unroll
          for (int q = 0; q < 4; ++q){
            float v = acc[q] + bv;
            if (sg) v = sigm(v);
            sst16(&projB[(size_t)(r0 + q)*1808 + cc], f2bf(v));
            if (cc == 1792) ast32(&rgcur[r0 + q], __float_as_uint(v));
          }
        } else if (t >= 1){
          do_readout(jid - 1808, t, mctx, Fold, er, bout2, x, out, lane);
        }
      }
    }
    gbar(leaf, root, ++nbar);
    // ---- phase D: attention + memory update (block = batch bid) ----
    {
      // stage projB row -> LDS (f32)
      const unsigned* p32 = (const unsigned*)(projB + (size_t)bid*1808);
      for (int i = tid; i < 904; i += 512){
        unsigned u = ald32(p32 + i);
        float f0 = bf2f((unsigned short)(u & 0xFFFFu));
        float f1 = bf2f((unsigned short)(u >> 16));
        int j = i*2;
        if (j < 1024){ qkW[j>>8][j&255] = f0; qkW[j>>8][(j&255)+1] = f1; }
        else if (j < 1280){ qkW[4][j-1024] = f0; qkW[4][j-1023] = f1; }
        else if (j < 1536){ wvs[j-1280] = f0; wvs[j-1279] = f1; }
        else if (j < 1792){ er[j-1536] = f0; er[j-1535] = f1; }
        else { wgS = f1; }
      }
      __syncthreads();
      const float wgv = wgS;
      // pass1: scores (vectorized b128)
      {
        const int n = tid & 127, quarter = tid >> 7, db = quarter*64;
        const float* mr = &memL[n][db];
        floatx4 A0={0,0,0,0},A1={0,0,0,0},A2={0,0,0,0},A3={0,0,0,0},A4={0,0,0,0};
        #pragma unroll 4
        for (int i = 0; i < 64; i += 4){
          floatx4 m4 = *(const floatx4*)(mr + i);
          floatx4 q0 = *(const floatx4*)&qkW[0][db+i];
          floatx4 q1 = *(const floatx4*)&qkW[1][db+i];
          floatx4 q2 = *(const floatx4*)&qkW[2][db+i];
          floatx4 q3 = *(const floatx4*)&qkW[3][db+i];
          floatx4 qw = *(const floatx4*)&qkW[4][db+i];
          A0 += m4*q0; A1 += m4*q1; A2 += m4*q2; A3 += m4*q3; A4 += m4*qw;
        }
        scU[0][tid] = A0[0]+A0[1]+A0[2]+A0[3];
        scU[1][tid] = A1[0]+A1[1]+A1[2]+A1[3];
        scU[2][tid] = A2[0]+A2[1]+A2[2]+A2[3];
        scU[3][tid] = A3[0]+A3[1]+A3[2]+A3[3];
        scU[4][tid] = A4[0]+A4[1]+A4[2]+A4[3];
      }
      __syncthreads();
      if (tid < 128){
        #pragma unroll
        for (int j = 0; j < 5; ++j){
          float v = scU[j][tid] + scU[j][tid+128] + scU[j][tid+256] + scU[j][tid+384];
          scU[j][tid] = (j < 4) ? v * 0.125f : v;
        }
      }
      __syncthreads();
      {
        const int w = tid >> 6, l = tid & 63;
        if (w < 5){
          const int j = w;
          float v0 = scU[j][l], v1 = scU[j][l + 64];
          float mx = fmaxf(v0, v1);
          #pragma unroll
          for (int off = 32; off; off >>= 1) mx = fmaxf(mx, __shfl_xor(mx, off));
          float e0 = __expf(v0 - mx), e1 = __expf(v1 - mx);
          float sm = e0 + e1;
          #pragma unroll
          for (int off = 32; off; off >>= 1) sm += __shfl_xor(sm, off);
          float inv = 1.f / sm;
          attT[l][j] = e0 * inv; attT[l + 64][j] = e1 * inv;
        }
      }
      __syncthreads();
      // pass2: mctx = at . mem (vector-scalar fma, b128 att broadcast)
      floatx4 M = {0,0,0,0};
      {
        const int d = tid & 255, n0 = (tid >> 8) * 64;
        #pragma unroll 4
        for (int n = n0; n < n0 + 64; ++n){
          floatx4 a4 = *(const floatx4*)&attT[n][0];
          float m = memL[n][d];
          M += a4 * m;
        }
        if (tid >= 256) mpart[d] = M;
      }
      __syncthreads();
      if (tid < 256){
        floatx4 M2 = M + mpart[tid];
        const unsigned lo = (unsigned)f2bf(M2[0]) | ((unsigned)f2bf(M2[1]) << 16);
        const unsigned hi = (unsigned)f2bf(M2[2]) | ((unsigned)f2bf(M2[3]) << 16);
        ast64((unsigned long long*)(mctx + (size_t)bid*1024) + tid,
              (unsigned long long)lo | ((unsigned long long)hi << 32));
      }
      __syncthreads();
      // memory erase/write update (vectorized, er/wv hoisted)
      {
        const int d4 = (tid & 63)*4, nw = tid >> 6;
        floatx4 er4 = *(const floatx4*)&er[d4];
        floatx4 wv4 = *(const floatx4*)&wvs[d4];
        #pragma unroll 4
        for (int k = 0; k < 16; ++k){
          const int n = nw + k*8;
          const float a = attT[n][4];
          floatx4 m = *(const floatx4*)&memL[n][d4];
          m = m * (1.f - a*er4) + (wgv*a) * wv4;
          *(floatx4*)&memL[n][d4] = m;
        }
      }
      // prefetch x(t+1) (cached) and h(t) (coherent, waited at next AB)
      {
        const int tn = (t+1 < S_LEN) ? t+1 : t;
        const unsigned short* ax = xbf + ((size_t)row*S_LEN + tn)*D_DIM + lk;
        #pragma unroll
        for (int kt = 0; kt < 8; ++kt) xfr[kt] = *(const bf16x8*)(ax + kt*32);
        cload16_issue(hw + (size_t)row*C_DIM + lk, hq);
      }
    }
    unsigned short* tmp = (unsigned short*)hr; hr = hw; hw = tmp;
  }
  gbar(leaf, root, ++nbar);
  // final readout (t = S_LEN)
  {
    if (tid < 256) er[tid] = __uint_as_float(ald32(&rgbuf[((S_LEN-1)&1)*256 + tid]));
    __syncthreads();
    const int slot = bid*8 + wave;
    if (slot < 256) do_readout(slot, S_LEN, mctx, Fold, er, bout2, x, out, lane);
  }
  for (int i = tid; i < 32768; i += 512)
    memT[(size_t)bid * 32768 + i] = memL[i >> 8][i & 255];
}

// ---------------- host ----------------

extern "C" void kernel_launch(void* const* d_in, const int* in_sizes, int n_in,
                              void* d_out, int out_size, void* d_ws, size_t ws_size,
                              hipStream_t stream){
  const float* x      = (const float*)d_in[0];
  const float* mem0   = (const float*)d_in[1];
  const float* Wih    = (const float*)d_in[2];
  const float* Whh    = (const float*)d_in[3];
  const float* bih    = (const float*)d_in[4];
  const float* bhh    = (const float*)d_in[5];
  const float* Wread  = (const float*)d_in[6];
  const float* bread  = (const float*)d_in[7];
  const float* Wwrite = (const float*)d_in[8];
  const float* bwrite = (const float*)d_in[9];
  const float* Werase = (const float*)d_in[10];
  const float* berase = (const float*)d_in[11];
  const float* Win    = (const float*)d_in[12];
  const float* bin    = (const float*)d_in[13];
  const float* Wout   = (const float*)d_in[14];
  const float* bout   = (const float*)d_in[15];
  const float* Wrg    = (const float*)d_in[16];
  const float* brg    = (const float*)d_in[17];
  const float* Wwg    = (const float*)d_in[18];
  const float* bwg    = (const float*)d_in[19];
  float* out = (float*)d_out;
  float* memT = out + (size_t)B_SZ * S_LEN * D_DIM;

  char* ws = (char*)d_ws;
  size_t off = 0;
  auto alloc = [&](size_t bytes) -> void* {
    void* p = ws + off; off += (bytes + 511) & ~(size_t)511; return p;
  };
  unsigned short* xbf  = (unsigned short*)alloc((size_t)B_SZ*S_LEN*D_DIM*2);
  unsigned short* Wg   = (unsigned short*)alloc((size_t)2048*768*2);
  unsigned short* W2   = (unsigned short*)alloc((size_t)1808*512*2);
  unsigned short* Fold = (unsigned short*)alloc((size_t)256*1024*2);
  float* T     = (float*)alloc((size_t)256*512*4);
  float* rq    = (float*)alloc(256*4);
  float* bias2 = (float*)alloc(1808*4);
  float* bout2 = (float*)alloc(256*4);
  float* biasg = (float*)alloc(2048*4);
  float* cbuf  = (float*)alloc((size_t)256*512*4);
  unsigned short* h0 = (unsigned short*)alloc((size_t)256*512*2);
  unsigned short* h1 = (unsigned short*)alloc((size_t)256*512*2);
  unsigned short* projB = (unsigned short*)alloc((size_t)256*1808*2);
  unsigned short* mctx = (unsigned short*)alloc((size_t)256*1024*2);
  float* rgbuf = (float*)alloc(512*4);
  unsigned* barcnt = (unsigned*)alloc(4096);
  (void)ws_size; (void)in_sizes; (void)n_in; (void)out_size;

  (void)hipMemsetAsync(barcnt, 0, 4096, stream);
  p0_xbf <<<16384, 256, 0, stream>>>(x, xbf);
  p1_wg  <<<6144, 256, 0, stream>>>(Wih, Whh, Wg);
  p2_T   <<<513,  256, 0, stream>>>(Win, Wread, bread, bin, T, rq);
  p3_w2  <<<3624, 256, 0, stream>>>(Win, Wwrite, Werase, Wrg, Wwg, bwrite, berase, brg, bwg, T, rq, W2, bias2);
  p4_fold<<<1025, 256, 0, stream>>>(Win, Wout, bout, bin, Fold, bout2);
  p5_init<<<512,  256, 0, stream>>>(bih, bhh, biasg, cbuf, h0);

  kmain<<<NBLK, 512, 0, stream>>>(x, xbf, Wg, biasg, W2, bias2, Fold, bout2,
                                  cbuf, h0, h1, projB, mctx, rgbuf, mem0, memT, out, barcnt);
}

// Round 8
// 8915.102 us; speedup vs baseline: 2.2154x; 1.2759x over previous
//
#include <hip/hip_runtime.h>

#define S_LEN 256
#define B_SZ  256
#define N_MEM 128
#define D_DIM 256
#define C_DIM 512
#define NBLK  256
#define MSTR  260   // memL row stride (f32): 16B-aligned rows, b128 conflict-free
#define AGENT __HIP_MEMORY_SCOPE_AGENT

typedef __bf16 bf16x8 __attribute__((ext_vector_type(8)));
typedef unsigned short ushort4v __attribute__((ext_vector_type(4)));
typedef float floatx4 __attribute__((ext_vector_type(4)));
typedef float floatx2 __attribute__((ext_vector_type(2)));

__device__ __forceinline__ unsigned short f2bf(float f){
  unsigned u = __float_as_uint(f);
  u += 0x7FFFu + ((u >> 16) & 1u);
  return (unsigned short)(u >> 16);
}
__device__ __forceinline__ float bf2f(unsigned short v){
  return __uint_as_float(((unsigned)v) << 16);
}
__device__ __forceinline__ float sigm(float x){ return 1.f/(1.f + __expf(-x)); }
__device__ __forceinline__ floatx4 mfma16(bf16x8 a, bf16x8 b, floatx4 c){
  return __builtin_amdgcn_mfma_f32_16x16x32_bf16(a, b, c, 0, 0, 0);
}

// ---- L3-coherent (agent-scope, relaxed) helpers ----
__device__ __forceinline__ unsigned ald32(const void* p){
  return __hip_atomic_load((const unsigned*)p, __ATOMIC_RELAXED, AGENT);
}
__device__ __forceinline__ void ast32(void* p, unsigned v){
  __hip_atomic_store((unsigned*)p, v, __ATOMIC_RELAXED, AGENT);
}
__device__ __forceinline__ void ast64(void* p, unsigned long long v){
  __hip_atomic_store((unsigned long long*)p, v, __ATOMIC_RELAXED, AGENT);
}
__device__ __forceinline__ void sst16(void* p, unsigned short v){
  asm volatile("global_store_short %0, %1, off sc1" :: "v"(p), "v"(v) : "memory");
}

struct V16 { floatx4 v0,v1,v2,v3,v4,v5,v6,v7,v8,v9,v10,v11,v12,v13,v14,v15; };
#define BC(xx) __builtin_bit_cast(bf16x8, xx)

// blocking variant: 16 coherent 16B loads + wait
__device__ __forceinline__ V16 cload16(const unsigned short* base){
  V16 r;
  asm volatile(
    "global_load_dwordx4 %0, %16, off sc1\n\t"
    "global_load_dwordx4 %1, %16, off offset:64 sc1\n\t"
    "global_load_dwordx4 %2, %16, off offset:128 sc1\n\t"
    "global_load_dwordx4 %3, %16, off offset:192 sc1\n\t"
    "global_load_dwordx4 %4, %16, off offset:256 sc1\n\t"
    "global_load_dwordx4 %5, %16, off offset:320 sc1\n\t"
    "global_load_dwordx4 %6, %16, off offset:384 sc1\n\t"
    "global_load_dwordx4 %7, %16, off offset:448 sc1\n\t"
    "global_load_dwordx4 %8, %16, off offset:512 sc1\n\t"
    "global_load_dwordx4 %9, %16, off offset:576 sc1\n\t"
    "global_load_dwordx4 %10, %16, off offset:640 sc1\n\t"
    "global_load_dwordx4 %11, %16, off offset:704 sc1\n\t"
    "global_load_dwordx4 %12, %16, off offset:768 sc1\n\t"
    "global_load_dwordx4 %13, %16, off offset:832 sc1\n\t"
    "global_load_dwordx4 %14, %16, off offset:896 sc1\n\t"
    "global_load_dwordx4 %15, %16, off offset:960 sc1\n\t"
    "s_waitcnt vmcnt(0)"
    : "=&v"(r.v0), "=&v"(r.v1), "=&v"(r.v2), "=&v"(r.v3),
      "=&v"(r.v4), "=&v"(r.v5), "=&v"(r.v6), "=&v"(r.v7),
      "=&v"(r.v8), "=&v"(r.v9), "=&v"(r.v10), "=&v"(r.v11),
      "=&v"(r.v12), "=&v"(r.v13), "=&v"(r.v14), "=&v"(r.v15)
    : "v"(base)
    : "memory");
  __builtin_amdgcn_sched_barrier(0);
  return r;
}

// split variant: issue now (no wait), wait later via cwait16
__device__ __forceinline__ void cload16_issue(const unsigned short* base, floatx4 r[16]){
  asm volatile(
    "global_load_dwordx4 %0, %16, off sc1\n\t"
    "global_load_dwordx4 %1, %16, off offset:64 sc1\n\t"
    "global_load_dwordx4 %2, %16, off offset:128 sc1\n\t"
    "global_load_dwordx4 %3, %16, off offset:192 sc1\n\t"
    "global_load_dwordx4 %4, %16, off offset:256 sc1\n\t"
    "global_load_dwordx4 %5, %16, off offset:320 sc1\n\t"
    "global_load_dwordx4 %6, %16, off offset:384 sc1\n\t"
    "global_load_dwordx4 %7, %16, off offset:448 sc1\n\t"
    "global_load_dwordx4 %8, %16, off offset:512 sc1\n\t"
    "global_load_dwordx4 %9, %16, off offset:576 sc1\n\t"
    "global_load_dwordx4 %10, %16, off offset:640 sc1\n\t"
    "global_load_dwordx4 %11, %16, off offset:704 sc1\n\t"
    "global_load_dwordx4 %12, %16, off offset:768 sc1\n\t"
    "global_load_dwordx4 %13, %16, off offset:832 sc1\n\t"
    "global_load_dwordx4 %14, %16, off offset:896 sc1\n\t"
    "global_load_dwordx4 %15, %16, off offset:960 sc1"
    : "=&v"(r[0]), "=&v"(r[1]), "=&v"(r[2]), "=&v"(r[3]),
      "=&v"(r[4]), "=&v"(r[5]), "=&v"(r[6]), "=&v"(r[7]),
      "=&v"(r[8]), "=&v"(r[9]), "=&v"(r[10]), "=&v"(r[11]),
      "=&v"(r[12]), "=&v"(r[13]), "=&v"(r[14]), "=&v"(r[15])
    : "v"(base)
    : "memory");
}
__device__ __forceinline__ void cwait16(floatx4 r[16]){
  asm volatile("s_waitcnt vmcnt(0)"
    : "+v"(r[0]), "+v"(r[1]), "+v"(r[2]), "+v"(r[3]),
      "+v"(r[4]), "+v"(r[5]), "+v"(r[6]), "+v"(r[7]),
      "+v"(r[8]), "+v"(r[9]), "+v"(r[10]), "+v"(r[11]),
      "+v"(r[12]), "+v"(r[13]), "+v"(r[14]), "+v"(r[15])
    :: "memory");
  __builtin_amdgcn_sched_barrier(0);
}

// ---------------- prologue kernels ----------------

__global__ __launch_bounds__(256) void p0_xbf(const float* __restrict__ x,
                                              unsigned short* __restrict__ xbf){
  int idx = (blockIdx.x*256 + threadIdx.x)*4;
  floatx4 f = *(const floatx4*)(x + idx);
  ushort4v u;
  u[0]=f2bf(f[0]); u[1]=f2bf(f[1]); u[2]=f2bf(f[2]); u[3]=f2bf(f[3]);
  *(ushort4v*)(xbf + idx) = u;
}

__global__ __launch_bounds__(256) void p1_wg(const float* __restrict__ Wih,
                                             const float* __restrict__ Whh,
                                             unsigned short* __restrict__ Wg){
  int idx = blockIdx.x*256 + threadIdx.x;
  int n = idx / 768, k = idx - n*768;
  float v = (k < 256) ? Wih[n*256 + k] : Whh[n*512 + (k-256)];
  Wg[idx] = f2bf(v);
}

__global__ __launch_bounds__(256) void p2_T(const float* __restrict__ Win,
                                            const float* __restrict__ Wread,
                                            const float* __restrict__ bread,
                                            const float* __restrict__ bin,
                                            float* __restrict__ T, float* __restrict__ rq){
  if (blockIdx.x < 512){
    int idx = blockIdx.x*256 + threadIdx.x;
    int e = idx >> 9, cc = idx & 511;
    float acc = 0.f;
    for (int dp = 0; dp < 256; ++dp) acc += Win[e*256 + dp] * Wread[dp*512 + cc];
    T[idx] = acc;
  } else {
    int e = threadIdx.x;
    float acc = bin[e];
    for (int dp = 0; dp < 256; ++dp) acc += bread[dp] * Win[e*256 + dp];
    rq[e] = acc;
  }
}

__global__ __launch_bounds__(256) void p3_w2(const float* __restrict__ Win,
                                             const float* __restrict__ Wwrite,
                                             const float* __restrict__ Werase,
                                             const float* __restrict__ Wrg,
                                             const float* __restrict__ Wwg,
                                             const float* __restrict__ bwrite,
                                             const float* __restrict__ berase,
                                             const float* __restrict__ brg,
                                             const float* __restrict__ bwg,
                                             const float* __restrict__ T,
                                             const float* __restrict__ rq,
                                             unsigned short* __restrict__ W2,
                                             float* __restrict__ bias2){
  int bid = blockIdx.x;
  if (bid < 2048){
    int idx = bid*256 + threadIdx.x;
    int j = idx >> 9, cc = idx & 511;
    int h = j >> 8, d = j & 255;
    float acc = 0.f;
    const float* wk = Win + (256 + h*64)*256 + d;
    const float* tp = T + (h*64)*512 + cc;
    for (int i = 0; i < 64; ++i) acc += wk[i*256] * tp[i*512];
    W2[(size_t)j*512 + cc] = f2bf(acc);
  } else if (bid < 2048 + 1568){
    int idx = (bid - 2048)*256 + threadIdx.x;
    int r = idx >> 9, cc = idx & 511;
    float v;
    if      (r < 512) v = Wwrite[r*512 + cc];
    else if (r < 768) v = Werase[(r-512)*512 + cc];
    else if (r == 768) v = Wrg[cc];
    else if (r == 769) v = Wwg[cc];
    else v = 0.f;
    W2[(size_t)(1024 + r)*512 + cc] = f2bf(v);
  } else {
    int j = (bid - 2048 - 1568)*256 + threadIdx.x;
    if (j >= 1808) return;
    float v;
    if (j < 1024){
      int h = j >> 8, d = j & 255;
      float acc = 0.f;
      for (int i = 0; i < 64; ++i) acc += rq[h*64+i] * Win[(256 + h*64 + i)*256 + d];
      v = acc;
    }
    else if (j < 1536) v = bwrite[j - 1024];
    else if (j < 1792) v = berase[j - 1536];
    else if (j == 1792) v = brg[0];
    else if (j == 1793) v = bwg[0];
    else v = 0.f;
    bias2[j] = v;
  }
}

// Fold: column j = d*4 + h (matches mctx u64-packed d-major layout)
__global__ __launch_bounds__(256) void p4_fold(const float* __restrict__ Win,
                                               const float* __restrict__ Wout,
                                               const float* __restrict__ bout,
                                               const float* __restrict__ bin,
                                               unsigned short* __restrict__ Fold,
                                               float* __restrict__ bout2){
  if (blockIdx.x < 1024){
    int idx = blockIdx.x*256 + threadIdx.x;
    int dp = idx >> 10, j = idx & 1023;
    int h = j & 3, d = j >> 2;
    float acc = 0.f;
    const float* wv = Win + (512 + h*64)*256 + d;
    const float* wo = Wout + dp*256 + h*64;
    for (int i = 0; i < 64; ++i) acc += wv[i*256] * wo[i];
    Fold[(size_t)dp*1024 + j] = f2bf(acc);
  } else {
    int dp = threadIdx.x;
    float acc = bout[dp];
    for (int e = 0; e < 256; ++e) acc += Wout[dp*256 + e] * bin[512 + e];
    bout2[dp] = acc;
  }
}

// zero c/h0, biasg = bih + bhh
__global__ __launch_bounds__(256) void p5_init(const float* __restrict__ bih,
                                               const float* __restrict__ bhh,
                                               float* __restrict__ biasg,
                                               float* __restrict__ c,
                                               unsigned short* __restrict__ h0){
  int idx = blockIdx.x*256 + threadIdx.x;
  c[idx] = 0.f; h0[idx] = 0;
  if (idx < 2048) biasg[idx] = bih[idx] + bhh[idx];
}

// ---------------- 16-block group barrier (relaxed adds + load-only spin) ----------------
// All communication is group-local (group g = blocks g*16..g*16+15), so each
// group syncs independently: 16 adds + 16 pollers on one 64B-spaced line.
__device__ __forceinline__ void gbarg(unsigned* cnt, unsigned nb){
  __syncthreads();
  if (threadIdx.x == 0){
    __hip_atomic_fetch_add(cnt, 1u, __ATOMIC_RELAXED, AGENT);
    while (__hip_atomic_load(cnt, __ATOMIC_RELAXED, AGENT) < nb*16u)
      __builtin_amdgcn_s_sleep(1);
  }
  __builtin_amdgcn_sched_barrier(0);
  __syncthreads();
}

// ---------------- persistent kernel ----------------

__device__ __forceinline__ void do_readout(int mt, int dt, int t,
                                           const unsigned short* __restrict__ mctx,
                                           const unsigned short* __restrict__ Fold,
                                           const float* __restrict__ rgb,
                                           const float* __restrict__ bout2,
                                           const float* __restrict__ x,
                                           float* __restrict__ out, int lane){
  const int lm = lane & 15, lk = (lane >> 4) * 8;
  const unsigned short* ap = mctx + (size_t)(mt*16 + lm)*1024 + lk;
  const unsigned short* bp = Fold + (size_t)(dt*16 + lm)*1024 + lk;
  const int r0 = mt*16 + ((lane >> 4) << 2);
  // issue rg loads early (coherent), consumed in epilogue
  float rg0 = __uint_as_float(ald32(&rgb[r0]));
  float rg1 = __uint_as_float(ald32(&rgb[r0+1]));
  float rg2 = __uint_as_float(ald32(&rgb[r0+2]));
  float rg3 = __uint_as_float(ald32(&rgb[r0+3]));
  V16 a0 = cload16(ap);
  V16 a1 = cload16(ap + 512);
  const bf16x8 av[16] = {BC(a0.v0),BC(a0.v1),BC(a0.v2),BC(a0.v3),BC(a0.v4),BC(a0.v5),BC(a0.v6),BC(a0.v7),
                         BC(a0.v8),BC(a0.v9),BC(a0.v10),BC(a0.v11),BC(a0.v12),BC(a0.v13),BC(a0.v14),BC(a0.v15)};
  const bf16x8 bv[16] = {BC(a1.v0),BC(a1.v1),BC(a1.v2),BC(a1.v3),BC(a1.v4),BC(a1.v5),BC(a1.v6),BC(a1.v7),
                         BC(a1.v8),BC(a1.v9),BC(a1.v10),BC(a1.v11),BC(a1.v12),BC(a1.v13),BC(a1.v14),BC(a1.v15)};
  floatx4 acc = {0,0,0,0};
  #pragma unroll
  for (int kt = 0; kt < 16; ++kt)
    acc = mfma16(av[kt], *(const bf16x8*)(bp + kt*32), acc);
  #pragma unroll
  for (int kt = 0; kt < 16; ++kt)
    acc = mfma16(bv[kt], *(const bf16x8*)(bp + 512 + kt*32), acc);
  const int dp = dt*16 + lm;
  const float bo = bout2[dp];
  const float rg[4] = {rg0, rg1, rg2, rg3};
  #pragma unroll
  for (int q = 0; q < 4; ++q){
    const int bb = r0 + q;
    const size_t oi = ((size_t)bb * S_LEN + (t-1)) * D_DIM + dp;
    out[oi] = x[oi] + rg[q] * (acc[q] + bo);
  }
}

__global__ __launch_bounds__(512, 2) void kmain(
    const float* __restrict__ x,
    const unsigned short* __restrict__ xbf,
    const unsigned short* __restrict__ Wg,
    const float* __restrict__ biasg,
    const unsigned short* __restrict__ W2, const float* __restrict__ bias2,
    const unsigned short* __restrict__ Fold, const float* __restrict__ bout2,
    float* __restrict__ cbuf,
    unsigned short* __restrict__ h0buf, unsigned short* __restrict__ h1buf,
    unsigned short* __restrict__ projB, unsigned short* __restrict__ mctx,
    float* __restrict__ rgbuf, const float* __restrict__ mem0,
    float* __restrict__ memT, float* __restrict__ out,
    unsigned* __restrict__ barcnt)
{
  const int bid = blockIdx.x, tid = threadIdx.x;
  const int lane = tid & 63, wave = tid >> 6;
  const int lm = lane & 15, lk = (lane >> 4) * 8;

  __shared__ float memL[128][MSTR];   // 133120 B (persistent)
  __shared__ float scU[5][512];       //  10240 B (AB: ga / D: scores,mctx-partial)
  __shared__ float qkW[5][256];       //   5120 B
  __shared__ float er[256];           //   1024 B
  __shared__ float wvs[256];          //   1024 B
  __shared__ float attT[128][8];      //   4096 B
  __shared__ float wgS;
  float (*ga)[16][32] = (float (*)[16][32])&scU[0][0];
  floatx4* mpart = (floatx4*)&scU[0][0];

  const int r = bid >> 4, uc = bid & 15, u0 = uc*32;
  unsigned* gcnt = barcnt + r*16;     // 64B-spaced per-group counter

  for (int i = tid; i < 32768; i += 512) memL[i >> 8][i & 255] = mem0[i];

  unsigned nbar = 0;
  const unsigned short* hr = h0buf;
  unsigned short* hw = h1buf;
  const int g = wave >> 1, colh = wave & 1;
  const int row = r*16 + lm;
  const int slot = uc*8 + wave;       // 0..127 within group

  // prologue prefetch: h(-1)=0 buffer + x(0)
  floatx4 hq[16];
  bf16x8 xfr[8];
  cload16_issue(hr + (size_t)row*C_DIM + lk, hq);
  {
    const unsigned short* ax = xbf + ((size_t)row*S_LEN + 0)*D_DIM + lk;
    #pragma unroll
    for (int kt = 0; kt < 8; ++kt) xfr[kt] = *(const bf16x8*)(ax + kt*32);
  }

  for (int t = 0; t < S_LEN; ++t){
    // ---- phase AB: gates GEMM + LSTM ----
    {
      const unsigned short* wb = Wg + (size_t)(g*512 + u0 + colh*16 + lm)*768 + lk;
      cwait16(hq);                         // h(t-1) prefetched during D(t-1)
      floatx4 acc = {0,0,0,0};
      #pragma unroll
      for (int kt = 0; kt < 8; ++kt)
        acc = mfma16(xfr[kt], *(const bf16x8*)(wb + kt*32), acc);
      #pragma unroll
      for (int kt = 0; kt < 16; ++kt)
        acc = mfma16(BC(hq[kt]), *(const bf16x8*)(wb + 256 + kt*32), acc);
      const int rr0 = (lane >> 4) << 2;
      #pragma unroll
      for (int q = 0; q < 4; ++q) ga[g][rr0+q][colh*16 + lm] = acc[q];
      __syncthreads();
      if (tid < 256){
        const int ri = tid >> 4, cp = (tid & 15) * 2;
        const int b = r*16 + ri, u = u0 + cp;
        floatx2 bg0 = *(const floatx2*)&biasg[u];
        floatx2 bg1 = *(const floatx2*)&biasg[512 + u];
        floatx2 bg2 = *(const floatx2*)&biasg[1024 + u];
        floatx2 bg3 = *(const floatx2*)&biasg[1536 + u];
        const float gi0 = ga[0][ri][cp]   + bg0[0];
        const float gf0 = ga[1][ri][cp]   + bg1[0];
        const float gg0 = ga[2][ri][cp]   + bg2[0];
        const float go0 = ga[3][ri][cp]   + bg3[0];
        const float gi1 = ga[0][ri][cp+1] + bg0[1];
        const float gf1 = ga[1][ri][cp+1] + bg1[1];
        const float gg1 = ga[2][ri][cp+1] + bg2[1];
        const float go1 = ga[3][ri][cp+1] + bg3[1];
        const int ci2 = b*512 + u;
        floatx2 cv = *(const floatx2*)&cbuf[ci2];
        const float cn0 = sigm(gf0) * cv[0] + sigm(gi0) * tanhf(gg0);
        const float cn1 = sigm(gf1) * cv[1] + sigm(gi1) * tanhf(gg1);
        floatx2 cw; cw[0] = cn0; cw[1] = cn1;
        *(floatx2*)&cbuf[ci2] = cw;
        const unsigned hv2 = (unsigned)f2bf(sigm(go0) * tanhf(cn0))
                           | ((unsigned)f2bf(sigm(go1) * tanhf(cn1)) << 16);
        ast32((unsigned*)hw + (ci2 >> 1), hv2);
      }
    }
    gbarg(gcnt, ++nbar);
    // ---- phase C (group-local): 113 proj tiles + 16 readouts over 128 slots ----
    {
      const float* rgprev = rgbuf + ((t-1)&1)*256;
      float* rgcur = rgbuf + (t&1)*256;
      for (int j = slot; j < 129; j += 128){
        if (j < 113){
          const int nt = j;                     // mt = r (group-local rows)
          const unsigned short* ap = hw + (size_t)(r*16 + lm)*512 + lk;
          const unsigned short* bp = W2 + (size_t)(nt*16 + lm)*512 + lk;
          V16 av16 = cload16(ap);
          const bf16x8 av[16] = {BC(av16.v0),BC(av16.v1),BC(av16.v2),BC(av16.v3),BC(av16.v4),BC(av16.v5),BC(av16.v6),BC(av16.v7),
                                 BC(av16.v8),BC(av16.v9),BC(av16.v10),BC(av16.v11),BC(av16.v12),BC(av16.v13),BC(av16.v14),BC(av16.v15)};
          floatx4 acc = {0,0,0,0};
          #pragma unroll
          for (int kt = 0; kt < 16; ++kt)
            acc = mfma16(av[kt], *(const bf16x8*)(bp + kt*32), acc);
          const int r0 = r*16 + ((lane >> 4) << 2);
          const int cc = nt*16 + lm;
          const float bv = bias2[cc];
          const bool sg = (cc >= 1536 && cc < 1794);
          #pragma unroll
          for (int q = 0; q < 4; ++q){
            float v = acc[q] + bv;
            if (sg) v = sigm(v);
            sst16(&projB[(size_t)(r0 + q)*1808 + cc], f2bf(v));
            if (cc == 1792) ast32(&rgcur[r0 + q], __float_as_uint(v));
          }
        } else if (t >= 1){
          do_readout(r, j - 113, t, mctx, Fold, rgprev, bout2, x, out, lane);
        }
      }
    }
    gbarg(gcnt, ++nbar);
    // ---- phase D: attention + memory update (block = batch bid) ----
    {
      // stage projB row -> LDS (f32)
      const unsigned* p32 = (const unsigned*)(projB + (size_t)bid*1808);
      for (int i = tid; i < 904; i += 512){
        unsigned u = ald32(p32 + i);
        float f0 = bf2f((unsigned short)(u & 0xFFFFu));
        float f1 = bf2f((unsigned short)(u >> 16));
        int j = i*2;
        if (j < 1024){ qkW[j>>8][j&255] = f0; qkW[j>>8][(j&255)+1] = f1; }
        else if (j < 1280){ qkW[4][j-1024] = f0; qkW[4][j-1023] = f1; }
        else if (j < 1536){ wvs[j-1280] = f0; wvs[j-1279] = f1; }
        else if (j < 1792){ er[j-1536] = f0; er[j-1535] = f1; }
        else { wgS = f1; }
      }
      __syncthreads();
      const float wgv = wgS;
      // pass1: scores (vectorized b128)
      {
        const int n = tid & 127, quarter = tid >> 7, db = quarter*64;
        const float* mr = &memL[n][db];
        floatx4 A0={0,0,0,0},A1={0,0,0,0},A2={0,0,0,0},A3={0,0,0,0},A4={0,0,0,0};
        #pragma unroll 4
        for (int i = 0; i < 64; i += 4){
          floatx4 m4 = *(const floatx4*)(mr + i);
          floatx4 q0 = *(const floatx4*)&qkW[0][db+i];
          floatx4 q1 = *(const floatx4*)&qkW[1][db+i];
          floatx4 q2 = *(const floatx4*)&qkW[2][db+i];
          floatx4 q3 = *(const floatx4*)&qkW[3][db+i];
          floatx4 qw = *(const floatx4*)&qkW[4][db+i];
          A0 += m4*q0; A1 += m4*q1; A2 += m4*q2; A3 += m4*q3; A4 += m4*qw;
        }
        scU[0][tid] = A0[0]+A0[1]+A0[2]+A0[3];
        scU[1][tid] = A1[0]+A1[1]+A1[2]+A1[3];
        scU[2][tid] = A2[0]+A2[1]+A2[2]+A2[3];
        scU[3][tid] = A3[0]+A3[1]+A3[2]+A3[3];
        scU[4][tid] = A4[0]+A4[1]+A4[2]+A4[3];
      }
      __syncthreads();
      if (tid < 128){
        #pragma unroll
        for (int j = 0; j < 5; ++j){
          float v = scU[j][tid] + scU[j][tid+128] + scU[j][tid+256] + scU[j][tid+384];
          scU[j][tid] = (j < 4) ? v * 0.125f : v;
        }
      }
      __syncthreads();
      {
        const int w = tid >> 6, l = tid & 63;
        if (w < 5){
          const int j = w;
          float v0 = scU[j][l], v1 = scU[j][l + 64];
          float mx = fmaxf(v0, v1);
          #pragma unroll
          for (int off = 32; off; off >>= 1) mx = fmaxf(mx, __shfl_xor(mx, off));
          float e0 = __expf(v0 - mx), e1 = __expf(v1 - mx);
          float sm = e0 + e1;
          #pragma unroll
          for (int off = 32; off; off >>= 1) sm += __shfl_xor(sm, off);
          float inv = 1.f / sm;
          attT[l][j] = e0 * inv; attT[l + 64][j] = e1 * inv;
        }
      }
      __syncthreads();
      // pass2: mctx = at . mem (vector-scalar fma, b128 att broadcast)
      floatx4 M = {0,0,0,0};
      {
        const int d = tid & 255, n0 = (tid >> 8) * 64;
        #pragma unroll 4
        for (int n = n0; n < n0 + 64; ++n){
          floatx4 a4 = *(const floatx4*)&attT[n][0];
          float m = memL[n][d];
          M += a4 * m;
        }
        if (tid >= 256) mpart[d] = M;
      }
      __syncthreads();
      if (tid < 256){
        floatx4 M2 = M + mpart[tid];
        const unsigned lo = (unsigned)f2bf(M2[0]) | ((unsigned)f2bf(M2[1]) << 16);
        const unsigned hi = (unsigned)f2bf(M2[2]) | ((unsigned)f2bf(M2[3]) << 16);
        ast64((unsigned long long*)(mctx + (size_t)bid*1024) + tid,
              (unsigned long long)lo | ((unsigned long long)hi << 32));
      }
      __syncthreads();
      // memory erase/write update (vectorized, er/wv hoisted)
      {
        const int d4 = (tid & 63)*4, nw = tid >> 6;
        floatx4 er4 = *(const floatx4*)&er[d4];
        floatx4 wv4 = *(const floatx4*)&wvs[d4];
        #pragma unroll 4
        for (int k = 0; k < 16; ++k){
          const int n = nw + k*8;
          const float a = attT[n][4];
          floatx4 m = *(const floatx4*)&memL[n][d4];
          m = m * (1.f - a*er4) + (wgv*a) * wv4;
          *(floatx4*)&memL[n][d4] = m;
        }
      }
      // prefetch x(t+1) (cached) and h(t) (coherent, waited at next AB)
      {
        const int tn = (t+1 < S_LEN) ? t+1 : t;
        const unsigned short* ax = xbf + ((size_t)row*S_LEN + tn)*D_DIM + lk;
        #pragma unroll
        for (int kt = 0; kt < 8; ++kt) xfr[kt] = *(const bf16x8*)(ax + kt*32);
        cload16_issue(hw + (size_t)row*C_DIM + lk, hq);
      }
    }
    unsigned short* tmp = (unsigned short*)hr; hr = hw; hw = tmp;
  }
  gbarg(gcnt, ++nbar);
  // final readout (t = S_LEN): one job per block (mt=r, dt=uc)
  if (wave == 0)
    do_readout(r, uc, S_LEN, mctx, Fold, rgbuf + ((S_LEN-1)&1)*256, bout2, x, out, lane);
  for (int i = tid; i < 32768; i += 512)
    memT[(size_t)bid * 32768 + i] = memL[i >> 8][i & 255];
}

// ---------------- host ----------------

extern "C" void kernel_launch(void* const* d_in, const int* in_sizes, int n_in,
                              void* d_out, int out_size, void* d_ws, size_t ws_size,
                              hipStream_t stream){
  const float* x      = (const float*)d_in[0];
  const float* mem0   = (const float*)d_in[1];
  const float* Wih    = (const float*)d_in[2];
  const float* Whh    = (const float*)d_in[3];
  const float* bih    = (const float*)d_in[4];
  const float* bhh    = (const float*)d_in[5];
  const float* Wread  = (const float*)d_in[6];
  const float* bread  = (const float*)d_in[7];
  const float* Wwrite = (const float*)d_in[8];
  const float* bwrite = (const float*)d_in[9];
  const float* Werase = (const float*)d_in[10];
  const float* berase = (const float*)d_in[11];
  const float* Win    = (const float*)d_in[12];
  const float* bin    = (const float*)d_in[13];
  const float* Wout   = (const float*)d_in[14];
  const float* bout   = (const float*)d_in[15];
  const float* Wrg    = (const float*)d_in[16];
  const float* brg    = (const float*)d_in[17];
  const float* Wwg    = (const float*)d_in[18];
  const float* bwg    = (const float*)d_in[19];
  float* out = (float*)d_out;
  float* memT = out + (size_t)B_SZ * S_LEN * D_DIM;

  char* ws = (char*)d_ws;
  size_t off = 0;
  auto alloc = [&](size_t bytes) -> void* {
    void* p = ws + off; off += (bytes + 511) & ~(size_t)511; return p;
  };
  unsigned short* xbf  = (unsigned short*)alloc((size_t)B_SZ*S_LEN*D_DIM*2);
  unsigned short* Wg   = (unsigned short*)alloc((size_t)2048*768*2);
  unsigned short* W2   = (unsigned short*)alloc((size_t)1808*512*2);
  unsigned short* Fold = (unsigned short*)alloc((size_t)256*1024*2);
  float* T     = (float*)alloc((size_t)256*512*4);
  float* rq    = (float*)alloc(256*4);
  float* bias2 = (float*)alloc(1808*4);
  float* bout2 = (float*)alloc(256*4);
  float* biasg = (float*)alloc(2048*4);
  float* cbuf  = (float*)alloc((size_t)256*512*4);
  unsigned short* h0 = (unsigned short*)alloc((size_t)256*512*2);
  unsigned short* h1 = (unsigned short*)alloc((size_t)256*512*2);
  unsigned short* projB = (unsigned short*)alloc((size_t)256*1808*2);
  unsigned short* mctx = (unsigned short*)alloc((size_t)256*1024*2);
  float* rgbuf = (float*)alloc(512*4);
  unsigned* barcnt = (unsigned*)alloc(4096);
  (void)ws_size; (void)in_sizes; (void)n_in; (void)out_size;

  (void)hipMemsetAsync(barcnt, 0, 4096, stream);
  p0_xbf <<<16384, 256, 0, stream>>>(x, xbf);
  p1_wg  <<<6144, 256, 0, stream>>>(Wih, Whh, Wg);
  p2_T   <<<513,  256, 0, stream>>>(Win, Wread, bread, bin, T, rq);
  p3_w2  <<<3624, 256, 0, stream>>>(Win, Wwrite, Werase, Wrg, Wwg, bwrite, berase, brg, bwg, T, rq, W2, bias2);
  p4_fold<<<1025, 256, 0, stream>>>(Win, Wout, bout, bin, Fold, bout2);
  p5_init<<<512,  256, 0, stream>>>(bih, bhh, biasg, cbuf, h0);

  kmain<<<NBLK, 512, 0, stream>>>(x, xbf, Wg, biasg, W2, bias2, Fold, bout2,
                                  cbuf, h0, h1, projB, mctx, rgbuf, mem0, memT, out, barcnt);
}